// Round 7
// baseline (901.332 us; speedup 1.0000x reference)
//
#include <hip/hip_runtime.h>
#include <hip/hip_bf16.h>
#include <math.h>
#include <cstdio>

// TMSA block, fp32 I/O, bf16 MFMA internals, pre-packed bf16 weights.
// ws layout (bytes):
//   [0,          37748736)   xw    bf16 [98304][192]  (LN1 out; later LN2 out)
//   [37748736,  75497472)    xwm   bf16 [98304][192]  (xw + pos_bias)
//   [75497472,  150994944)   attn  bf16 [98304][384]  (attn out; later MLP hidden)
//   [150994944, 264241152)   qkv   bf16 [3][4608][128][32] (hd pad 30->32, q pre-scaled)
//   [264241152, 264634368)   biasrT bf16 [6][128 col][128 row] (transposed rpb gather)
//   [264634368, 265671168)   packed weights/biases (see offsets in launch)
// res (x + proj) lives in d_out (fp32), updated in-place by fc2.

typedef __hip_bfloat16 bf16;
typedef __attribute__((ext_vector_type(8))) short short8;
typedef __attribute__((ext_vector_type(4))) unsigned short us4;
typedef __attribute__((ext_vector_type(4))) float f32x4;

#define SCALE_F 0.18257418583505536f   // 30^-0.5
#define SZPE 18874368u                 // elems per qkv tensor: 4608*128*32

__device__ __forceinline__ bf16  f2b(float v){ return __float2bfloat16(v); }
__device__ __forceinline__ float bu2f(unsigned short u){
    union { unsigned int i; float f; } x; x.i = ((unsigned int)u) << 16; return x.f;
}
__device__ __forceinline__ f32x4 mfma16(short8 a, short8 b, f32x4 c){
    return __builtin_amdgcn_mfma_f32_16x16x32_bf16(a, b, c, 0, 0, 0);
}

// fast gelu with exact-erf semantics: A&S 7.1.26, |err(erf)| <= 1.5e-7
// (invisible under bf16 output rounding). ~13 VALU + 1 trans vs ~35 for erff.
__device__ __forceinline__ float gelu_erf(float x){
    float z  = fabsf(x) * 0.70710678118654752f;
    float t  = __builtin_amdgcn_rcpf(fmaf(0.3275911f, z, 1.f));
    float p  = fmaf(fmaf(fmaf(fmaf(1.061405429f, t, -1.453152027f),
                              t, 1.421413741f), t, -0.284496736f), t, 0.254829592f) * t;
    float e  = __expf(-z * z);
    float er = fmaf(-p, e, 1.f);          // erf(z), z >= 0
    er = (x >= 0.f) ? er : -er;
    return 0.5f * x * (1.f + er);
}

// XCD-aware bijective block swizzle: consecutive work ids land on one XCD.
// All GEMM grids are multiples of 8.
__device__ __forceinline__ int xswz(){
    return (blockIdx.x & 7) * ((int)gridDim.x >> 3) + ((int)blockIdx.x >> 3);
}

// Swin region label for (window, token): mask[win][i][j] == 0 iff label_i == label_j.
__device__ __forceinline__ int wincnt(int win, int tok){
    int d = (win >> 8) * 2 + (tok >> 6);
    int h = ((win >> 4) & 15) * 8 + ((tok >> 3) & 7);
    int w = (win & 15) * 8 + (tok & 7);
    int rd = (d >= 4) + (d >= 5);
    int rh = (h >= 120) + (h >= 124);
    int rw = (w >= 120) + (w >= 124);
    return (rd * 3 + rh) * 3 + rw;
}

// window-reverse + roll: token row -> fp32 base offset (elements) in [D][H][W][C]
__device__ __forceinline__ size_t wrev_base(int row){
    int win = row >> 7, tok = row & 127;
    int wd = win >> 8, wh = (win >> 4) & 15, ww = win & 15;
    int td = tok >> 6, th = (tok >> 3) & 7, tw = tok & 7;
    int d = wd * 2 + td + 1; if (d >= 6) d -= 6;
    int h = (wh * 8 + th + 4) & 127;
    int wcol = (ww * 8 + tw + 4) & 127;
    return ((size_t)((d * 128 + h) * 128 + wcol)) * 180;
}

// ---------------------------------------------------------------- weight packing
__global__ __launch_bounds__(256) void k_pack_qkv(const float* __restrict__ w,
                                                  const float* __restrict__ bias,
                                                  bf16* __restrict__ Bt,
                                                  float* __restrict__ bb)
{
    int idx = blockIdx.x * 256 + threadIdx.x;      // < 110592
    int n = idx / 192, k = idx - n * 192;
    int three = n / 192;
    int rem = n - three * 192, nh = rem >> 5, hdp = rem & 31;
    int srcc = three * 180 + nh * 30 + hdp;
    float v = 0.f;
    if (hdp < 30 && k < 180) v = w[(size_t)k * 540 + srcc];
    if (three == 0) v *= SCALE_F;
    Bt[(size_t)n * 192 + k] = f2b(v);
    if (k == 0) bb[n] = (hdp < 30) ? ((three == 0 ? SCALE_F : 1.f) * bias[srcc]) : 0.f;
}

// generic: Bt[n][k] (NP x KP) = w[k][n] (K x NW), zero-padded.
__global__ __launch_bounds__(256) void k_pack(const float* __restrict__ w,
                                              int NW, int K, int KP,
                                              bf16* __restrict__ Bt)
{
    int idx = blockIdx.x * 256 + threadIdx.x;
    int n = idx / KP, k = idx - n * KP;
    float v = (n < NW && k < K) ? w[(size_t)k * NW + n] : 0.f;
    Bt[idx] = f2b(v);
}

// ---------------------------------------------------------------- rpb gather (transposed, bf16)
__global__ __launch_bounds__(256) void k_rpbg(const float* __restrict__ rpb,
                                              const int* __restrict__ rpi,
                                              bf16* __restrict__ biasrT)
{
    int n = blockIdx.x * 256 + threadIdx.x;       // < 98304
    int nh = n >> 14, rc = n & 16383;
    int row = rc >> 7, col = rc & 127;
    biasrT[((size_t)nh * 128 + col) * 128 + row] = f2b(rpb[rpi[rc] * 6 + nh]);
}

// zero attn pad cols 360..383 (stride-384 buffer)
__global__ __launch_bounds__(256) void k_zpad(bf16* __restrict__ attn)
{
    int gi = blockIdx.x * 256 + threadIdx.x;      // < 294912
    int row = gi / 3, part = gi - row * 3;
    *(uint4*)&attn[(size_t)row * 384 + 360 + part * 8] = make_uint4(0u,0u,0u,0u);
}

// ---------------------------------------------------------------- LayerNorm
template<bool ROLL_PB>
__global__ __launch_bounds__(256) void k_ln(const float* __restrict__ x,
                                            const float* __restrict__ g,
                                            const float* __restrict__ b,
                                            const float* __restrict__ pb,
                                            bf16* __restrict__ xw,
                                            bf16* __restrict__ xwm)
{
    int row  = blockIdx.x * 4 + (threadIdx.x >> 6);
    int lane = threadIdx.x & 63;
    const float* src;
    if (ROLL_PB) {
        src = x + wrev_base(row);      // forward roll == (d+1, h+4, w+4) mapping
    } else {
        src = x + (size_t)row * 180;
    }
    float v0 = src[lane];
    float v1 = src[lane + 64];
    float v2 = (lane < 52) ? src[lane + 128] : 0.f;
    float s  = v0 + v1 + v2;
    float ss = v0*v0 + v1*v1 + v2*v2;
    #pragma unroll
    for (int o = 32; o > 0; o >>= 1) { s += __shfl_xor(s, o, 64); ss += __shfl_xor(ss, o, 64); }
    float mean = s * (1.f/180.f);
    float var  = ss * (1.f/180.f) - mean*mean;
    float rstd = rsqrtf(var + 1e-5f);

    bf16* dst = xw + (size_t)row * 192;
    float y0 = (v0-mean)*rstd*g[lane]     + b[lane];
    float y1 = (v1-mean)*rstd*g[lane+64]  + b[lane+64];
    float y2 = (lane < 52) ? ((v2-mean)*rstd*g[lane+128] + b[lane+128]) : 0.f;
    dst[lane]      = f2b(y0);
    dst[lane+64]   = f2b(y1);
    if (lane < 52) dst[lane+128] = f2b(y2);
    if (lane < 12) dst[180+lane] = f2b(0.f);
    if (ROLL_PB) {
        const float* pbr = pb + (size_t)(row & 63) * 180;
        bf16* dm = xwm + (size_t)row * 192;
        dm[lane]      = f2b(y0 + pbr[lane]);
        dm[lane+64]   = f2b(y1 + pbr[lane+64]);
        if (lane < 52) dm[lane+128] = f2b(y2 + pbr[lane+128]);
        if (lane < 12) dm[180+lane] = f2b(0.f);
    }
}

// ---------------------------------------------------------------- MFMA GEMM core v5
// C[128 x 64] tile of A[M x KP](bf16) @ Bt[N][KP](bf16, pre-transposed).
// NO LDS, NO barriers: MFMA fragments are 16B-contiguous in both operands'
// layouts, loaded straight from global into VGPRs (k_attn's proven pattern).
// A is L3-resident (each element read by exactly one wave -> LDS buys nothing);
// B is a <=221KB weight panel, L2-hot under the XCD swizzle. The compiler
// hoists/pipelines the loads across the fully-unrolled K-loop -- the thing
// the 2-barrier-per-K-step staging structure forbade (r4/r5 lesson).
template<int KP, bool DUAL>
__device__ __forceinline__ void mm3(const bf16* __restrict__ A,
                                    const bf16* __restrict__ Bt1,
                                    const bf16* __restrict__ Bt2,
                                    int m0, int n0,
                                    f32x4 (&acc1)[2][4], f32x4 (&acc2)[2][4])
{
    const int tid = threadIdx.x;
    const int w = tid >> 6, l = tid & 63, q = l >> 4, c = l & 15;
    const bf16* a0p = A + (size_t)(m0 + w * 32 + c) * KP + q * 8;      // mt=0 row
    const bf16* a1p = a0p + (size_t)16 * KP;                           // mt=1 row
    const bf16* bp  = Bt1 + (size_t)(n0 + c) * KP + q * 8;
    const bf16* b2p = DUAL ? (Bt2 + (size_t)(n0 + c) * KP + q * 8) : nullptr;
    #pragma unroll
    for (int ks = 0; ks < KP / 32; ks++) {
        short8 a0 = *(const short8*)(a0p + ks * 32);
        short8 a1 = *(const short8*)(a1p + ks * 32);
        #pragma unroll
        for (int nt = 0; nt < 4; nt++) {
            short8 b1 = *(const short8*)(bp + (size_t)(nt * 16) * KP + ks * 32);
            acc1[0][nt] = mfma16(a0, b1, acc1[0][nt]);
            acc1[1][nt] = mfma16(a1, b1, acc1[1][nt]);
            if (DUAL) {
                short8 b2 = *(const short8*)(b2p + (size_t)(nt * 16) * KP + ks * 32);
                acc2[0][nt] = mfma16(a0, b2, acc2[0][nt]);
                acc2[1][nt] = mfma16(a1, b2, acc2[1][nt]);
            }
        }
    }
}

// epilogue LDS roundtrip swizzle (bf16 path): chunk ^= (row>>2)&7.
__device__ __forceinline__ int cs_idx(int row, int colt){
    return row * 64 + ((((colt >> 3) ^ ((row >> 2) & 7)) << 3) | (colt & 7));
}

// qkv GEMM: KP=192, N=576 packed; vectorized scatter to qkv via LDS roundtrip.
__global__ __launch_bounds__(256) void k_qkv(const bf16* __restrict__ A,
                                             const bf16* __restrict__ Bt,
                                             const float* __restrict__ bb,
                                             bf16* __restrict__ outq)
{
    __shared__ __align__(16) bf16 Cs[128 * 64];
    int bid = xswz();                             // 6912 = 768 * 9, n-fastest
    int n0 = (bid % 9) * 64, m0 = (bid / 9) * 128;
    f32x4 a1[2][4] = {}, a2[2][4];
    mm3<192, false>(A, Bt, nullptr, m0, n0, a1, a2);

    int tid = threadIdx.x, w = tid >> 6, l = tid & 63, q = l >> 4, c = l & 15;
    #pragma unroll
    for (int mt = 0; mt < 2; mt++)
      #pragma unroll
      for (int nt = 0; nt < 4; nt++)
        #pragma unroll
        for (int r = 0; r < 4; r++) {
            int row = w * 32 + mt * 16 + q * 4 + r;
            int colt = nt * 16 + c;
            Cs[cs_idx(row, colt)] = f2b(a1[mt][nt][r] + bb[n0 + colt]);
        }
    __syncthreads();
    int win = m0 >> 7;
    #pragma unroll
    for (int e = 0; e < 4; e++) {
        int gi = e * 256 + tid;                   // < 1024
        int row = gi >> 3, j = gi & 7, c8 = j * 8;
        int col = n0 + c8;
        int three = col / 192, rem = col - three * 192;
        int nh = rem >> 5, hdp = rem & 31;
        bf16* dst = outq + (size_t)three * SZPE + ((size_t)(win * 6 + nh) * 128 + row) * 32 + hdp;
        *(uint4*)dst = *(const uint4*)&Cs[row * 64 + ((j ^ ((row >> 2) & 7)) << 3)];
    }
}

// proj GEMM: KP=384 (attn stride), N pad 192; window-reverse + roll + residual -> d_out.
// Epilogue: fp32 LDS roundtrip in two 64-row half-passes ([64][76] pad), then
// float4-coalesced xin read + res write (16 lanes cover 256B/row).
__global__ __launch_bounds__(256) void k_proj(const bf16* __restrict__ A,
                                              const bf16* __restrict__ Bt,
                                              const float* __restrict__ bias,
                                              const float* __restrict__ xin,
                                              float* __restrict__ res)
{
    __shared__ __align__(16) float Cs[64 * 76];   // 19456 B
    int bid = xswz();                             // 2304 = 768 * 3
    int n0 = (bid % 3) * 64, m0 = (bid / 3) * 128;
    f32x4 a1[2][4] = {}, a2[2][4];
    mm3<384, false>(A, Bt, nullptr, m0, n0, a1, a2);

    int tid = threadIdx.x, w = tid >> 6, l = tid & 63, q = l >> 4, c = l & 15;
    #pragma unroll
    for (int h = 0; h < 2; h++) {
        __syncthreads();                          // prev readers of Cs done
        if ((w >> 1) == h) {                      // waves 2h,2h+1 own rows h*64..+63
            #pragma unroll
            for (int mt = 0; mt < 2; mt++)
              #pragma unroll
              for (int nt = 0; nt < 4; nt++)
                #pragma unroll
                for (int r = 0; r < 4; r++) {
                    int rl = (w & 1) * 32 + mt * 16 + q * 4 + r;   // 0..63
                    Cs[rl * 76 + nt * 16 + c] = a1[mt][nt][r];
                }
        }
        __syncthreads();
        #pragma unroll
        for (int e = 0; e < 4; e++) {
            int slot = e * 256 + tid;             // < 1024: 64 rows x 16 quads
            int rl = slot >> 4, cq = slot & 15;
            int col = n0 + cq * 4;
            if (col < 180) {
                size_t base = wrev_base(m0 + h * 64 + rl) + col;
                float4 xi = *(const float4*)&xin[base];
                float4 bi = *(const float4*)&bias[col];
                const float* cp = &Cs[rl * 76 + cq * 4];
                float4 o;
                o.x = xi.x + cp[0] + bi.x;
                o.y = xi.y + cp[1] + bi.y;
                o.z = xi.z + cp[2] + bi.z;
                o.w = xi.w + cp[3] + bi.w;
                *(float4*)&res[base] = o;
            }
        }
    }
}

// fc1: KP=192, N pad 384 dual; gelu(x1)*x2 -> hid [98304][384] via LDS roundtrip.
__global__ __launch_bounds__(256) void k_fc1(const bf16* __restrict__ A,
                                             const bf16* __restrict__ Bt1,
                                             const float* __restrict__ bb1,
                                             const bf16* __restrict__ Bt2,
                                             const float* __restrict__ bb2,
                                             bf16* __restrict__ hid)
{
    __shared__ __align__(16) bf16 Cs[128 * 64];
    int bid = xswz();                             // 4608 = 768 * 6
    int n0 = (bid % 6) * 64, m0 = (bid / 6) * 128;
    f32x4 a1[2][4] = {}, a2[2][4] = {};
    mm3<192, true>(A, Bt1, Bt2, m0, n0, a1, a2);

    int tid = threadIdx.x, w = tid >> 6, l = tid & 63, q = l >> 4, c = l & 15;
    #pragma unroll
    for (int mt = 0; mt < 2; mt++)
      #pragma unroll
      for (int nt = 0; nt < 4; nt++)
        #pragma unroll
        for (int r = 0; r < 4; r++) {
            int row = w * 32 + mt * 16 + q * 4 + r;
            int colt = nt * 16 + c;
            int col = n0 + colt;
            float hv = 0.f;
            if (col < 360)
                hv = gelu_erf(a1[mt][nt][r] + bb1[col]) * (a2[mt][nt][r] + bb2[col]);
            Cs[cs_idx(row, colt)] = f2b(hv);
        }
    __syncthreads();
    #pragma unroll
    for (int e = 0; e < 4; e++) {
        int gi = e * 256 + tid;
        int row = gi >> 3, j = gi & 7, c8 = j * 8;
        *(uint4*)&hid[(size_t)(m0 + row) * 384 + n0 + c8] =
            *(const uint4*)&Cs[row * 64 + ((j ^ ((row >> 2) & 7)) << 3)];
    }
}

// fc2: KP=384 (hid stride), N pad 192; out += hid@w2 + b (in-place fp32).
// Same fp32-roundtrip + float4 RMW epilogue as proj (rows linear here).
__global__ __launch_bounds__(256) void k_fc2(const bf16* __restrict__ A,
                                             const bf16* __restrict__ Bt,
                                             const float* __restrict__ bias,
                                             float* __restrict__ out)
{
    __shared__ __align__(16) float Cs[64 * 76];   // 19456 B
    int bid = xswz();                             // 2304
    int n0 = (bid % 3) * 64, m0 = (bid / 3) * 128;
    f32x4 a1[2][4] = {}, a2[2][4];
    mm3<384, false>(A, Bt, nullptr, m0, n0, a1, a2);

    int tid = threadIdx.x, w = tid >> 6, l = tid & 63, q = l >> 4, c = l & 15;
    #pragma unroll
    for (int h = 0; h < 2; h++) {
        __syncthreads();
        if ((w >> 1) == h) {
            #pragma unroll
            for (int mt = 0; mt < 2; mt++)
              #pragma unroll
              for (int nt = 0; nt < 4; nt++)
                #pragma unroll
                for (int r = 0; r < 4; r++) {
                    int rl = (w & 1) * 32 + mt * 16 + q * 4 + r;
                    Cs[rl * 76 + nt * 16 + c] = a1[mt][nt][r];
                }
        }
        __syncthreads();
        #pragma unroll
        for (int e = 0; e < 4; e++) {
            int slot = e * 256 + tid;
            int rl = slot >> 4, cq = slot & 15;
            int col = n0 + cq * 4;
            if (col < 180) {
                size_t idx = (size_t)(m0 + h * 64 + rl) * 180 + col;
                float4 ov = *(const float4*)&out[idx];
                float4 bi = *(const float4*)&bias[col];
                const float* cp = &Cs[rl * 76 + cq * 4];
                ov.x += cp[0] + bi.x;
                ov.y += cp[1] + bi.y;
                ov.z += cp[2] + bi.z;
                ov.w += cp[3] + bi.w;
                *(float4*)&out[idx] = ov;
            }
        }
    }
}

// ---------------------------------------------------------------- MFMA attention v2
// Q/K fragments loaded direct from global; mask analytic; bias from transposed
// bf16 table; Vts/Ps XOR-swizzled; LDS 43520B -> 3 blocks/CU.
template<bool MUT>
__global__ __launch_bounds__(256) void k_attn(const bf16* __restrict__ qkv,
                                              const bf16* __restrict__ biasrT,
                                              bf16* __restrict__ aout)
{
    __shared__ __align__(16) bf16 Vts[32 * 136];
    __shared__ __align__(16) bf16 Ps[128 * 136];

    int wh = blockIdx.x, win = wh / 6, nh = wh - win * 6;
    const bf16* qg = qkv + (size_t)wh * 4096;
    const bf16* kg = qg + (size_t)SZPE;
    const bf16* vg = qg + 2 * (size_t)SZPE;
    int tid = threadIdx.x, w = tid >> 6, l = tid & 63, q = l >> 4, c = l & 15;

    // stage V transposed (swizzled): 2 x uint4 global loads per thread
    #pragma unroll
    for (int e = 0; e < 2; e++) {
        int base = (e * 256 + tid) * 8;          // < 4096
        int tok = base >> 5, hd0 = base & 31;
        uint4 vv = *(const uint4*)&vg[base];
        const bf16* pv = (const bf16*)&vv;
        #pragma unroll
        for (int i = 0; i < 8; i++) {
            int hd = hd0 + i;
            Vts[hd * 136 + (tok ^ (((hd >> 3) & 3) << 3))] = pv[i];
        }
    }

    // QK^T direct from global (A/B fragments are contiguous 16B in [128][32] layout)
    f32x4 S[2][8];
    #pragma unroll
    for (int mt = 0; mt < 2; mt++)
        #pragma unroll
        for (int nt = 0; nt < 8; nt++) S[mt][nt] = (f32x4){0.f, 0.f, 0.f, 0.f};
    {
        short8 a[2];
        #pragma unroll
        for (int mt = 0; mt < 2; mt++) {
            int rq = w * 32 + mt * 16 + c;
            if (MUT) rq ^= 64;                   // swap halves for mutual attn
            a[mt] = *(const short8*)&qg[rq * 32 + q * 8];
        }
        #pragma unroll
        for (int nt = 0; nt < 8; nt++) {
            short8 b = *(const short8*)&kg[(nt * 16 + c) * 32 + q * 8];
            #pragma unroll
            for (int mt = 0; mt < 2; mt++) S[mt][nt] = mfma16(a[mt], b, S[mt][nt]);
        }
    }

    // region labels for analytic mask
    int rcnt[2][4], ccnt[8];
    #pragma unroll
    for (int mt = 0; mt < 2; mt++)
        #pragma unroll
        for (int r = 0; r < 4; r++) {
            int row = w * 32 + mt * 16 + q * 4 + r;
            rcnt[mt][r] = wincnt(win, MUT ? (row & 63) : row);
        }
    #pragma unroll
    for (int nt = 0; nt < 8; nt++) {
        int col = nt * 16 + c;
        ccnt[nt] = wincnt(win, MUT ? (col & 63) : col);
    }

    float mx[2][4];
    #pragma unroll
    for (int mt = 0; mt < 2; mt++)
      #pragma unroll
      for (int r = 0; r < 4; r++) mx[mt][r] = -3.0e38f;

    #pragma unroll
    for (int mt = 0; mt < 2; mt++)
      #pragma unroll
      for (int nt = 0; nt < 8; nt++) {
        float bv[4];
        if (!MUT) {
            int col = nt * 16 + c;
            us4 bb = *(const us4*)&biasrT[((size_t)(nh * 128 + col)) * 128
                                          + w * 32 + mt * 16 + q * 4];
            #pragma unroll
            for (int r = 0; r < 4; r++) bv[r] = bu2f(bb[r]);
        }
        bool valid = (w < 2) == (nt < 4);        // wave-uniform (MUT only)
        #pragma unroll
        for (int r = 0; r < 4; r++) {
            float s = S[mt][nt][r];
            if (MUT) {
                s = (rcnt[mt][r] == ccnt[nt]) ? s : s - 100.f;
                s = valid ? s : -30000.f;
            } else {
                s += bv[r];
                if (rcnt[mt][r] != ccnt[nt]) s -= 100.f;
            }
            S[mt][nt][r] = s;
            mx[mt][r] = fmaxf(mx[mt][r], s);
        }
      }
    #pragma unroll
    for (int mt = 0; mt < 2; mt++)
      #pragma unroll
      for (int r = 0; r < 4; r++) {
          float m = mx[mt][r];
          #pragma unroll
          for (int o = 1; o < 16; o <<= 1) m = fmaxf(m, __shfl_xor(m, o, 64));
          mx[mt][r] = m;
      }

    float sm[2][4] = {};
    #pragma unroll
    for (int mt = 0; mt < 2; mt++)
      #pragma unroll
      for (int nt = 0; nt < 8; nt++)
        #pragma unroll
        for (int r = 0; r < 4; r++) {
            float p = __expf(S[mt][nt][r] - mx[mt][r]);
            sm[mt][r] += p;
            Ps[(w * 32 + mt * 16 + q * 4 + r) * 136 + ((nt * 16 + c) ^ (q << 3))] = f2b(p);
        }
    #pragma unroll
    for (int mt = 0; mt < 2; mt++)
      #pragma unroll
      for (int r = 0; r < 4; r++) {
          float s = sm[mt][r];
          #pragma unroll
          for (int o = 1; o < 16; o <<= 1) s += __shfl_xor(s, o, 64);
          sm[mt][r] = s;
      }
    __syncthreads();                              // Vts + Ps ready

    f32x4 O[2][2];
    #pragma unroll
    for (int mt = 0; mt < 2; mt++)
        #pragma unroll
        for (int nt = 0; nt < 2; nt++) O[mt][nt] = (f32x4){0.f, 0.f, 0.f, 0.f};
    #pragma unroll
    for (int ks = 0; ks < 4; ks++) {
        short8 a[2];
        #pragma unroll
        for (int mt = 0; mt < 2; mt++) {
            int row = w * 32 + mt * 16 + c;
            int xr = ((c >> 2) & 3) << 3;         // = (row>>2)&3, matches writer q
            a[mt] = *(const short8*)&Ps[row * 136 + (ks * 32 + ((q << 3) ^ xr))];
        }
        #pragma unroll
        for (int nt = 0; nt < 2; nt++) {
            int hd = nt * 16 + c;
            int xv = ((hd >> 3) & 3) << 3;
            short8 b = *(const short8*)&Vts[hd * 136 + (ks * 32 + ((q << 3) ^ xv))];
            #pragma unroll
            for (int mt = 0; mt < 2; mt++) O[mt][nt] = mfma16(a[mt], b, O[mt][nt]);
        }
    }

    #pragma unroll
    for (int mt = 0; mt < 2; mt++)
      #pragma unroll
      for (int r = 0; r < 4; r++) {
          int row = w * 32 + mt * 16 + q * 4 + r;
          float inv = 1.f / sm[mt][r];
          #pragma unroll
          for (int nt = 0; nt < 2; nt++) {
              int col = nt * 16 + c;
              if (col < 30)
                  aout[((size_t)win * 128 + row) * 384 + (MUT ? 0 : 180) + nh * 30 + col] =
                      f2b(O[mt][nt][r] * inv);
          }
      }
}

// ---------------------------------------------------------------- launch
extern "C" void kernel_launch(void* const* d_in, const int* in_sizes, int n_in,
                              void* d_out, int out_size, void* d_ws, size_t ws_size,
                              hipStream_t stream)
{
    const float* x     = (const float*)d_in[0];
    const float* mask  = (const float*)d_in[1];
    const float* g1    = (const float*)d_in[2];
    const float* b1    = (const float*)d_in[3];
    const float* g2    = (const float*)d_in[4];
    const float* b2    = (const float*)d_in[5];
    const float* wqs   = (const float*)d_in[6];
    const float* bqs   = (const float*)d_in[7];
    const float* wqm   = (const float*)d_in[8];
    const float* bqm   = (const float*)d_in[9];
    const float* rpb   = (const float*)d_in[10];
    const float* posb  = (const float*)d_in[11];
    const float* wproj = (const float*)d_in[12];
    const float* bproj = (const float*)d_in[13];
    const float* w11   = (const float*)d_in[14];
    const float* bf11  = (const float*)d_in[15];
    const float* w12   = (const float*)d_in[16];
    const float* bf12  = (const float*)d_in[17];
    const float* w2    = (const float*)d_in[18];
    const float* bf2   = (const float*)d_in[19];
    const int*   rpi   = (const int*)d_in[20];
    float* out = (float*)d_out;
    (void)mask;   // mask is computed analytically in k_attn

    const size_t need = 265671168;
    if (ws_size < need) { fprintf(stderr, "[tmsa] ws too small: %zu < %zu\n", ws_size, need); return; }

    char* W = (char*)d_ws;
    bf16*  xw     = (bf16*)W;                              // [98304][192]
    bf16*  xwm    = (bf16*)(W + 37748736);                 // [98304][192]
    bf16*  attn   = (bf16*)(W + 75497472);                 // [98304][384]
    bf16*  qkv    = (bf16*)(W + 150994944);                // [3][4608][128][32]
    bf16*  biasrT = (bf16*)(W + 264241152);                // [6][128][128] bf16 (transposed)
    bf16*  Btqs   = (bf16*)(W + 264634368);                // [576][192]
    bf16*  Btqm   = (bf16*)(W + 264855552);                // [576][192]
    float* bbqs   = (float*)(W + 265076736);               // [576]
    float* bbqm   = (float*)(W + 265079040);               // [576]
    bf16*  Btproj = (bf16*)(W + 265081344);                // [192][384]
    bf16*  Btf11  = (bf16*)(W + 265228800);                // [384][192]
    bf16*  Btf12  = (bf16*)(W + 265376256);                // [384][192]
    bf16*  Btf2   = (bf16*)(W + 265523712);                // [192][384]

    k_rpbg<<<dim3(384), 256, 0, stream>>>(rpb, rpi, biasrT);
    k_pack_qkv<<<dim3(432), 256, 0, stream>>>(wqs, bqs, Btqs, bbqs);
    k_pack_qkv<<<dim3(432), 256, 0, stream>>>(wqm, bqm, Btqm, bbqm);
    k_pack<<<dim3(288), 256, 0, stream>>>(wproj, 180, 360, 384, Btproj);
    k_pack<<<dim3(288), 256, 0, stream>>>(w11,   360, 180, 192, Btf11);
    k_pack<<<dim3(288), 256, 0, stream>>>(w12,   360, 180, 192, Btf12);
    k_pack<<<dim3(288), 256, 0, stream>>>(w2,    180, 360, 384, Btf2);

    k_ln<true><<<dim3(24576), 256, 0, stream>>>(x, g1, b1, posb, xw, xwm);
    k_zpad<<<dim3(1152), 256, 0, stream>>>(attn);
    k_qkv<<<dim3(6912), 256, 0, stream>>>(xw, Btqs, bbqs, qkv);
    k_attn<false><<<dim3(4608), 256, 0, stream>>>(qkv, biasrT, attn);
    k_qkv<<<dim3(6912), 256, 0, stream>>>(xwm, Btqm, bbqm, qkv);
    k_attn<true><<<dim3(4608), 256, 0, stream>>>(qkv, biasrT, attn);
    k_proj<<<dim3(2304), 256, 0, stream>>>(attn, Btproj, bproj, x, out);
    k_ln<false><<<dim3(24576), 256, 0, stream>>>(out, g2, b2, nullptr, xw, nullptr);
    k_fc1<<<dim3(4608), 256, 0, stream>>>(xw, Btf11, bf11, Btf12, bf12, attn);
    k_fc2<<<dim3(2304), 256, 0, stream>>>(attn, Btf2, bf2, out);
}

// Round 8
// 611.961 us; speedup vs baseline: 1.4729x; 1.4729x over previous
//
#include <hip/hip_runtime.h>
#include <hip/hip_bf16.h>
#include <math.h>
#include <cstdio>

// TMSA block, fp32 I/O, bf16 MFMA internals, pre-packed bf16 weights.
// ws layout (bytes):
//   [0,          37748736)   xw    bf16 [98304][192]  (LN1 out; later LN2 out)
//   [37748736,  75497472)    xwm   bf16 [98304][192]  (xw + pos_bias)
//   [75497472,  150994944)   attn  bf16 [98304][384]  (attn out; later MLP hidden)
//   [150994944, 264241152)   qkv   bf16 [3][4608][128][32] (hd pad 30->32, q pre-scaled)
//   [264241152, 264634368)   biasrT bf16 [6][128 col][128 row] (transposed rpb gather)
//   [264634368, 265671168)   packed weights/biases (see offsets in launch)
// res (x + proj) lives in d_out (fp32), updated in-place by fc2.

typedef __hip_bfloat16 bf16;
typedef __attribute__((ext_vector_type(8))) short short8;
typedef __attribute__((ext_vector_type(4))) unsigned short us4;
typedef __attribute__((ext_vector_type(4))) float f32x4;

#define SCALE_F 0.18257418583505536f   // 30^-0.5
#define SZPE 18874368u                 // elems per qkv tensor: 4608*128*32

__device__ __forceinline__ bf16  f2b(float v){ return __float2bfloat16(v); }
__device__ __forceinline__ float bu2f(unsigned short u){
    union { unsigned int i; float f; } x; x.i = ((unsigned int)u) << 16; return x.f;
}
__device__ __forceinline__ us4 pack4(float a, float b, float c, float d){
    us4 r;
    bf16 t0 = f2b(a), t1 = f2b(b), t2 = f2b(c), t3 = f2b(d);
    r[0] = *(unsigned short*)&t0; r[1] = *(unsigned short*)&t1;
    r[2] = *(unsigned short*)&t2; r[3] = *(unsigned short*)&t3;
    return r;
}
__device__ __forceinline__ f32x4 mfma16(short8 a, short8 b, f32x4 c){
    return __builtin_amdgcn_mfma_f32_16x16x32_bf16(a, b, c, 0, 0, 0);
}

// async global->LDS, 16B per lane; LDS dest is wave-uniform base + lane*16.
__device__ __forceinline__ void gld16(const bf16* g, bf16* s){
    __builtin_amdgcn_global_load_lds(
        (const __attribute__((address_space(1))) unsigned int*)g,
        (__attribute__((address_space(3))) unsigned int*)s, 16, 0, 0);
}

// fast gelu with exact-erf semantics: A&S 7.1.26, |err(erf)| <= 1.5e-7
// (invisible under bf16 output rounding). ~13 VALU + 1 trans vs ~35 for erff.
__device__ __forceinline__ float gelu_erf(float x){
    float z  = fabsf(x) * 0.70710678118654752f;
    float t  = __builtin_amdgcn_rcpf(fmaf(0.3275911f, z, 1.f));
    float p  = fmaf(fmaf(fmaf(fmaf(1.061405429f, t, -1.453152027f),
                              t, 1.421413741f), t, -0.284496736f), t, 0.254829592f) * t;
    float e  = __expf(-z * z);
    float er = fmaf(-p, e, 1.f);          // erf(z), z >= 0
    er = (x >= 0.f) ? er : -er;
    return 0.5f * x * (1.f + er);
}

// XCD-aware bijective block swizzle: consecutive work ids land on one XCD.
// All GEMM grids are multiples of 8.
__device__ __forceinline__ int xswz(){
    return (blockIdx.x & 7) * ((int)gridDim.x >> 3) + ((int)blockIdx.x >> 3);
}

// Swin region label for (window, token): mask[win][i][j] == 0 iff label_i == label_j.
__device__ __forceinline__ int wincnt(int win, int tok){
    int d = (win >> 8) * 2 + (tok >> 6);
    int h = ((win >> 4) & 15) * 8 + ((tok >> 3) & 7);
    int w = (win & 15) * 8 + (tok & 7);
    int rd = (d >= 4) + (d >= 5);
    int rh = (h >= 120) + (h >= 124);
    int rw = (w >= 120) + (w >= 124);
    return (rd * 3 + rh) * 3 + rw;
}

// window-reverse + roll: token row -> fp32 base offset (elements) in [D][H][W][C]
__device__ __forceinline__ size_t wrev_base(int row){
    int win = row >> 7, tok = row & 127;
    int wd = win >> 8, wh = (win >> 4) & 15, ww = win & 15;
    int td = tok >> 6, th = (tok >> 3) & 7, tw = tok & 7;
    int d = wd * 2 + td + 1; if (d >= 6) d -= 6;
    int h = (wh * 8 + th + 4) & 127;
    int wcol = (ww * 8 + tw + 4) & 127;
    return ((size_t)((d * 128 + h) * 128 + wcol)) * 180;
}

// ---------------------------------------------------------------- weight packing
__global__ __launch_bounds__(256) void k_pack_qkv(const float* __restrict__ w,
                                                  const float* __restrict__ bias,
                                                  bf16* __restrict__ Bt,
                                                  float* __restrict__ bb)
{
    int idx = blockIdx.x * 256 + threadIdx.x;      // < 110592
    int n = idx / 192, k = idx - n * 192;
    int three = n / 192;
    int rem = n - three * 192, nh = rem >> 5, hdp = rem & 31;
    int srcc = three * 180 + nh * 30 + hdp;
    float v = 0.f;
    if (hdp < 30 && k < 180) v = w[(size_t)k * 540 + srcc];
    if (three == 0) v *= SCALE_F;
    Bt[(size_t)n * 192 + k] = f2b(v);
    if (k == 0) bb[n] = (hdp < 30) ? ((three == 0 ? SCALE_F : 1.f) * bias[srcc]) : 0.f;
}

// generic: Bt[n][k] (NP x KP) = w[k][n] (K x NW), zero-padded.
__global__ __launch_bounds__(256) void k_pack(const float* __restrict__ w,
                                              int NW, int K, int KP,
                                              bf16* __restrict__ Bt)
{
    int idx = blockIdx.x * 256 + threadIdx.x;
    int n = idx / KP, k = idx - n * KP;
    float v = (n < NW && k < K) ? w[(size_t)k * NW + n] : 0.f;
    Bt[idx] = f2b(v);
}

// ---------------------------------------------------------------- rpb gather (transposed, bf16)
__global__ __launch_bounds__(256) void k_rpbg(const float* __restrict__ rpb,
                                              const int* __restrict__ rpi,
                                              bf16* __restrict__ biasrT)
{
    int n = blockIdx.x * 256 + threadIdx.x;       // < 98304
    int nh = n >> 14, rc = n & 16383;
    int row = rc >> 7, col = rc & 127;
    biasrT[((size_t)nh * 128 + col) * 128 + row] = f2b(rpb[rpi[rc] * 6 + nh]);
}

// zero attn pad cols 360..383 (stride-384 buffer)
__global__ __launch_bounds__(256) void k_zpad(bf16* __restrict__ attn)
{
    int gi = blockIdx.x * 256 + threadIdx.x;      // < 294912
    int row = gi / 3, part = gi - row * 3;
    *(uint4*)&attn[(size_t)row * 384 + 360 + part * 8] = make_uint4(0u,0u,0u,0u);
}

// ---------------------------------------------------------------- LayerNorm (vectorized)
// float4 loads: rows are 16B-aligned (180*4B = 720 ≡ 0 mod 16); 45 lanes/row.
// Stores as 8B bf16x4 (us4). Lanes 45..47 zero the pad cols 180..191.
template<bool ROLL_PB>
__global__ __launch_bounds__(256) void k_ln(const float* __restrict__ x,
                                            const float* __restrict__ g,
                                            const float* __restrict__ b,
                                            const float* __restrict__ pb,
                                            bf16* __restrict__ xw,
                                            bf16* __restrict__ xwm)
{
    int row  = blockIdx.x * 4 + (threadIdx.x >> 6);
    int lane = threadIdx.x & 63;
    const float* src = ROLL_PB ? (x + wrev_base(row)) : (x + (size_t)row * 180);
    float4 v = make_float4(0.f, 0.f, 0.f, 0.f);
    if (lane < 45) v = *(const float4*)&src[lane * 4];
    float s  = v.x + v.y + v.z + v.w;
    float ss = v.x*v.x + v.y*v.y + v.z*v.z + v.w*v.w;
    #pragma unroll
    for (int o = 32; o > 0; o >>= 1) { s += __shfl_xor(s, o, 64); ss += __shfl_xor(ss, o, 64); }
    float mean = s * (1.f/180.f);
    float var  = ss * (1.f/180.f) - mean*mean;
    float rstd = rsqrtf(var + 1e-5f);

    bf16* dst = xw + (size_t)row * 192;
    float4 y = make_float4(0.f, 0.f, 0.f, 0.f);
    if (lane < 45) {
        float4 gv = *(const float4*)&g[lane * 4];
        float4 bv = *(const float4*)&b[lane * 4];
        y.x = (v.x - mean) * rstd * gv.x + bv.x;
        y.y = (v.y - mean) * rstd * gv.y + bv.y;
        y.z = (v.z - mean) * rstd * gv.z + bv.z;
        y.w = (v.w - mean) * rstd * gv.w + bv.w;
        *(us4*)&dst[lane * 4] = pack4(y.x, y.y, y.z, y.w);
    } else if (lane < 48) {
        *(us4*)&dst[lane * 4] = (us4){0, 0, 0, 0};
    }
    if (ROLL_PB) {
        bf16* dm = xwm + (size_t)row * 192;
        if (lane < 45) {
            const float* pbr = pb + (size_t)(row & 63) * 180;
            float4 pv = *(const float4*)&pbr[lane * 4];
            *(us4*)&dm[lane * 4] = pack4(y.x + pv.x, y.y + pv.y, y.z + pv.z, y.w + pv.w);
        } else if (lane < 48) {
            *(us4*)&dm[lane * 4] = (us4){0, 0, 0, 0};
        }
    }
}

// ---------------------------------------------------------------- MFMA GEMM core v3
// C[128 x 64] tile of A[M x KP](bf16) @ Bt[N][KP](bf16, pre-transposed).
// Staging via global_load_lds width=16: LDS linear [rows][64], content
// chunk-swizzled (LDS[r][j] = G[r][j^(r&7)]) via pre-swizzled global source;
// ds_read applies the same XOR. Bank-even for all fragment reads.
template<int KP, bool DUAL>
__device__ __forceinline__ void mm2(const bf16* __restrict__ A,
                                    const bf16* __restrict__ Bt1,
                                    const bf16* __restrict__ Bt2,
                                    bf16* As, bf16* Bs1, bf16* Bs2,
                                    int m0, int n0,
                                    f32x4 (&acc1)[2][4], f32x4 (&acc2)[2][4])
{
    const int tid = threadIdx.x;
    const int w = tid >> 6, l = tid & 63, q = l >> 4, c = l & 15;
    const int lr = l >> 3, lj = l & 7;
    const int swz = ((lj ^ lr) << 3);             // pre-swizzled source chunk (elems)
    #pragma unroll
    for (int ks = 0; ks < KP / 64; ks++) {
        #pragma unroll
        for (int e = 0; e < 4; e++) {             // A: 128 rows, 8 rows per wave-load
            int m = (e * 4 + w) * 8 + lr;
            gld16(&A[(size_t)(m0 + m) * KP + ks * 64 + swz], &As[((e * 4 + w) * 8) * 64]);
        }
        #pragma unroll
        for (int e = 0; e < 2; e++) {             // B: 64 rows
            int n = (e * 4 + w) * 8 + lr;
            gld16(&Bt1[(size_t)(n0 + n) * KP + ks * 64 + swz], &Bs1[((e * 4 + w) * 8) * 64]);
            if (DUAL)
                gld16(&Bt2[(size_t)(n0 + n) * KP + ks * 64 + swz], &Bs2[((e * 4 + w) * 8) * 64]);
        }
        __syncthreads();                          // drains vmcnt (gld writes landed)
        #pragma unroll
        for (int k32 = 0; k32 < 2; k32++) {
            int koff = (((k32 * 4 + q) ^ (c & 7)) << 3);
            short8 a[2];
            #pragma unroll
            for (int mt = 0; mt < 2; mt++)
                a[mt] = *(const short8*)&As[(w * 32 + mt * 16 + c) * 64 + koff];
            #pragma unroll
            for (int nt = 0; nt < 4; nt++) {
                short8 b1 = *(const short8*)&Bs1[(nt * 16 + c) * 64 + koff];
                #pragma unroll
                for (int mt = 0; mt < 2; mt++) acc1[mt][nt] = mfma16(a[mt], b1, acc1[mt][nt]);
                if (DUAL) {
                    short8 b2 = *(const short8*)&Bs2[(nt * 16 + c) * 64 + koff];
                    #pragma unroll
                    for (int mt = 0; mt < 2; mt++) acc2[mt][nt] = mfma16(a[mt], b2, acc2[mt][nt]);
                }
            }
        }
        __syncthreads();
    }
}

// ---------------------------------------------------------------- MFMA GEMM core v6 (KP=192)
// B panel(s) staged FULLY once (segment-major [3][64][64], same swizzle) --
// only 24KB/operand; K-loop stages A only: 4 gld16 + 2 barriers per step
// (was 6-8 gld16). Barrier structure identical to proven v3.
template<bool DUAL>
__device__ __forceinline__ void mmh(const bf16* __restrict__ A,
                                    const bf16* __restrict__ Bt1,
                                    const bf16* __restrict__ Bt2,
                                    bf16* As, bf16* Bs1, bf16* Bs2,
                                    int m0, int n0,
                                    f32x4 (&acc1)[2][4], f32x4 (&acc2)[2][4])
{
    const int tid = threadIdx.x;
    const int w = tid >> 6, l = tid & 63, q = l >> 4, c = l & 15;
    const int lr = l >> 3, lj = l & 7;
    const int swz = ((lj ^ lr) << 3);             // pre-swizzled source chunk (elems)
    #pragma unroll
    for (int ks = 0; ks < 3; ks++)                // stage all B segments up front
      #pragma unroll
      for (int e = 0; e < 2; e++) {
        int n = (e * 4 + w) * 8 + lr;
        gld16(&Bt1[(size_t)(n0 + n) * 192 + ks * 64 + swz],
              &Bs1[ks * 4096 + ((e * 4 + w) * 8) * 64]);
        if (DUAL)
            gld16(&Bt2[(size_t)(n0 + n) * 192 + ks * 64 + swz],
                  &Bs2[ks * 4096 + ((e * 4 + w) * 8) * 64]);
      }
    #pragma unroll
    for (int ks = 0; ks < 3; ks++) {
        #pragma unroll
        for (int e = 0; e < 4; e++) {             // A: 128 rows, 8 rows per wave-load
            int m = (e * 4 + w) * 8 + lr;
            gld16(&A[(size_t)(m0 + m) * 192 + ks * 64 + swz], &As[((e * 4 + w) * 8) * 64]);
        }
        __syncthreads();                          // drains vmcnt (A now; B on first pass)
        #pragma unroll
        for (int k32 = 0; k32 < 2; k32++) {
            int koff = (((k32 * 4 + q) ^ (c & 7)) << 3);
            short8 a[2];
            #pragma unroll
            for (int mt = 0; mt < 2; mt++)
                a[mt] = *(const short8*)&As[(w * 32 + mt * 16 + c) * 64 + koff];
            #pragma unroll
            for (int nt = 0; nt < 4; nt++) {
                short8 b1 = *(const short8*)&Bs1[ks * 4096 + (nt * 16 + c) * 64 + koff];
                #pragma unroll
                for (int mt = 0; mt < 2; mt++) acc1[mt][nt] = mfma16(a[mt], b1, acc1[mt][nt]);
                if (DUAL) {
                    short8 b2 = *(const short8*)&Bs2[ks * 4096 + (nt * 16 + c) * 64 + koff];
                    #pragma unroll
                    for (int mt = 0; mt < 2; mt++) acc2[mt][nt] = mfma16(a[mt], b2, acc2[mt][nt]);
                }
            }
        }
        __syncthreads();                          // all waves done reading As
    }
}

// epilogue LDS roundtrip swizzle (bf16 path): chunk ^= (row>>2)&7.
__device__ __forceinline__ int cs_idx(int row, int colt){
    return row * 64 + ((((colt >> 3) ^ ((row >> 2) & 7)) << 3) | (colt & 7));
}

// qkv GEMM: KP=192, N=576 packed; vectorized scatter to qkv via LDS roundtrip.
__global__ __launch_bounds__(256) void k_qkv(const bf16* __restrict__ A,
                                             const bf16* __restrict__ Bt,
                                             const float* __restrict__ bb,
                                             bf16* __restrict__ outq)
{
    __shared__ __align__(16) bf16 As[128 * 64];
    __shared__ __align__(16) bf16 Bs[3 * 64 * 64];
    int bid = xswz();                             // 6912 = 768 * 9, n-fastest
    int n0 = (bid % 9) * 64, m0 = (bid / 9) * 128;
    f32x4 a1[2][4] = {}, a2[2][4];
    mmh<false>(A, Bt, nullptr, As, Bs, nullptr, m0, n0, a1, a2);

    int tid = threadIdx.x, w = tid >> 6, l = tid & 63, q = l >> 4, c = l & 15;
    bf16* Cs = As;
    #pragma unroll
    for (int mt = 0; mt < 2; mt++)
      #pragma unroll
      for (int nt = 0; nt < 4; nt++)
        #pragma unroll
        for (int r = 0; r < 4; r++) {
            int row = w * 32 + mt * 16 + q * 4 + r;
            int colt = nt * 16 + c;
            Cs[cs_idx(row, colt)] = f2b(a1[mt][nt][r] + bb[n0 + colt]);
        }
    __syncthreads();
    int win = m0 >> 7;
    #pragma unroll
    for (int e = 0; e < 4; e++) {
        int gi = e * 256 + tid;                   // < 1024
        int row = gi >> 3, j = gi & 7, c8 = j * 8;
        int col = n0 + c8;
        int three = col / 192, rem = col - three * 192;
        int nh = rem >> 5, hdp = rem & 31;
        bf16* dst = outq + (size_t)three * SZPE + ((size_t)(win * 6 + nh) * 128 + row) * 32 + hdp;
        *(uint4*)dst = *(const uint4*)&Cs[row * 64 + ((j ^ ((row >> 2) & 7)) << 3)];
    }
}

// proj GEMM: KP=384 (attn stride), N pad 192; window-reverse + roll + residual -> d_out.
// Epilogue: fp32 LDS roundtrip in two 64-row half-passes ([64][76] pad), then
// float4-coalesced xin read + res write (16 lanes cover 256B/row).
__global__ __launch_bounds__(256) void k_proj(const bf16* __restrict__ A,
                                              const bf16* __restrict__ Bt,
                                              const float* __restrict__ bias,
                                              const float* __restrict__ xin,
                                              float* __restrict__ res)
{
    __shared__ __align__(16) char smem[24576];
    bf16*  As = (bf16*)smem;                      // 16384 B
    bf16*  Bs = (bf16*)(smem + 16384);            // 8192 B
    float* Cs = (float*)smem;                     // [64][76] = 19456 B per half
    int bid = xswz();                             // 2304 = 768 * 3
    int n0 = (bid % 3) * 64, m0 = (bid / 3) * 128;
    f32x4 a1[2][4] = {}, a2[2][4];
    mm2<384, false>(A, Bt, nullptr, As, Bs, nullptr, m0, n0, a1, a2);

    int tid = threadIdx.x, w = tid >> 6, l = tid & 63, q = l >> 4, c = l & 15;
    #pragma unroll
    for (int h = 0; h < 2; h++) {
        __syncthreads();                          // prev readers of Cs/As done
        if ((w >> 1) == h) {                      // waves 2h,2h+1 own rows h*64..+63
            #pragma unroll
            for (int mt = 0; mt < 2; mt++)
              #pragma unroll
              for (int nt = 0; nt < 4; nt++)
                #pragma unroll
                for (int r = 0; r < 4; r++) {
                    int rl = (w & 1) * 32 + mt * 16 + q * 4 + r;   // 0..63
                    Cs[rl * 76 + nt * 16 + c] = a1[mt][nt][r];
                }
        }
        __syncthreads();
        #pragma unroll
        for (int e = 0; e < 4; e++) {
            int slot = e * 256 + tid;             // < 1024: 64 rows x 16 quads
            int rl = slot >> 4, cq = slot & 15;
            int col = n0 + cq * 4;
            if (col < 180) {
                size_t base = wrev_base(m0 + h * 64 + rl) + col;
                float4 xi = *(const float4*)&xin[base];
                float4 bi = *(const float4*)&bias[col];
                const float* cp = &Cs[rl * 76 + cq * 4];
                float4 o;
                o.x = xi.x + cp[0] + bi.x;
                o.y = xi.y + cp[1] + bi.y;
                o.z = xi.z + cp[2] + bi.z;
                o.w = xi.w + cp[3] + bi.w;
                *(float4*)&res[base] = o;
            }
        }
    }
}

// fc1: KP=192, N pad 384 dual; gelu(x1)*x2 -> hid [98304][384] via LDS roundtrip.
__global__ __launch_bounds__(256) void k_fc1(const bf16* __restrict__ A,
                                             const bf16* __restrict__ Bt1,
                                             const float* __restrict__ bb1,
                                             const bf16* __restrict__ Bt2,
                                             const float* __restrict__ bb2,
                                             bf16* __restrict__ hid)
{
    __shared__ __align__(16) bf16 As[128 * 64];
    __shared__ __align__(16) bf16 Bs1[3 * 64 * 64];
    __shared__ __align__(16) bf16 Bs2[3 * 64 * 64];
    int bid = xswz();                             // 4608 = 768 * 6
    int n0 = (bid % 6) * 64, m0 = (bid / 6) * 128;
    f32x4 a1[2][4] = {}, a2[2][4] = {};
    mmh<true>(A, Bt1, Bt2, As, Bs1, Bs2, m0, n0, a1, a2);

    int tid = threadIdx.x, w = tid >> 6, l = tid & 63, q = l >> 4, c = l & 15;
    bf16* Cs = As;
    #pragma unroll
    for (int mt = 0; mt < 2; mt++)
      #pragma unroll
      for (int nt = 0; nt < 4; nt++)
        #pragma unroll
        for (int r = 0; r < 4; r++) {
            int row = w * 32 + mt * 16 + q * 4 + r;
            int colt = nt * 16 + c;
            int col = n0 + colt;
            float hv = 0.f;
            if (col < 360)
                hv = gelu_erf(a1[mt][nt][r] + bb1[col]) * (a2[mt][nt][r] + bb2[col]);
            Cs[cs_idx(row, colt)] = f2b(hv);
        }
    __syncthreads();
    #pragma unroll
    for (int e = 0; e < 4; e++) {
        int gi = e * 256 + tid;
        int row = gi >> 3, j = gi & 7, c8 = j * 8;
        *(uint4*)&hid[(size_t)(m0 + row) * 384 + n0 + c8] =
            *(const uint4*)&Cs[row * 64 + ((j ^ ((row >> 2) & 7)) << 3)];
    }
}

// fc2: KP=384 (hid stride), N pad 192; out += hid@w2 + b (in-place fp32).
// Same fp32-roundtrip + float4 RMW epilogue as proj (rows linear here).
__global__ __launch_bounds__(256) void k_fc2(const bf16* __restrict__ A,
                                             const bf16* __restrict__ Bt,
                                             const float* __restrict__ bias,
                                             float* __restrict__ out)
{
    __shared__ __align__(16) char smem[24576];
    bf16*  As = (bf16*)smem;
    bf16*  Bs = (bf16*)(smem + 16384);
    float* Cs = (float*)smem;                     // [64][76]
    int bid = xswz();                             // 2304
    int n0 = (bid % 3) * 64, m0 = (bid / 3) * 128;
    f32x4 a1[2][4] = {}, a2[2][4];
    mm2<384, false>(A, Bt, nullptr, As, Bs, nullptr, m0, n0, a1, a2);

    int tid = threadIdx.x, w = tid >> 6, l = tid & 63, q = l >> 4, c = l & 15;
    #pragma unroll
    for (int h = 0; h < 2; h++) {
        __syncthreads();
        if ((w >> 1) == h) {
            #pragma unroll
            for (int mt = 0; mt < 2; mt++)
              #pragma unroll
              for (int nt = 0; nt < 4; nt++)
                #pragma unroll
                for (int r = 0; r < 4; r++) {
                    int rl = (w & 1) * 32 + mt * 16 + q * 4 + r;
                    Cs[rl * 76 + nt * 16 + c] = a1[mt][nt][r];
                }
        }
        __syncthreads();
        #pragma unroll
        for (int e = 0; e < 4; e++) {
            int slot = e * 256 + tid;
            int rl = slot >> 4, cq = slot & 15;
            int col = n0 + cq * 4;
            if (col < 180) {
                size_t idx = (size_t)(m0 + h * 64 + rl) * 180 + col;
                float4 ov = *(const float4*)&out[idx];
                float4 bi = *(const float4*)&bias[col];
                const float* cp = &Cs[rl * 76 + cq * 4];
                ov.x += cp[0] + bi.x;
                ov.y += cp[1] + bi.y;
                ov.z += cp[2] + bi.z;
                ov.w += cp[3] + bi.w;
                *(float4*)&out[idx] = ov;
            }
        }
    }
}

// ---------------------------------------------------------------- MFMA attention v2
// Q/K fragments loaded direct from global; mask analytic; bias from transposed
// bf16 table; Vts/Ps XOR-swizzled; LDS 43520B -> 3 blocks/CU.
template<bool MUT>
__global__ __launch_bounds__(256) void k_attn(const bf16* __restrict__ qkv,
                                              const bf16* __restrict__ biasrT,
                                              bf16* __restrict__ aout)
{
    __shared__ __align__(16) bf16 Vts[32 * 136];
    __shared__ __align__(16) bf16 Ps[128 * 136];

    int wh = blockIdx.x, win = wh / 6, nh = wh - win * 6;
    const bf16* qg = qkv + (size_t)wh * 4096;
    const bf16* kg = qg + (size_t)SZPE;
    const bf16* vg = qg + 2 * (size_t)SZPE;
    int tid = threadIdx.x, w = tid >> 6, l = tid & 63, q = l >> 4, c = l & 15;

    // stage V transposed (swizzled): 2 x uint4 global loads per thread
    #pragma unroll
    for (int e = 0; e < 2; e++) {
        int base = (e * 256 + tid) * 8;          // < 4096
        int tok = base >> 5, hd0 = base & 31;
        uint4 vv = *(const uint4*)&vg[base];
        const bf16* pv = (const bf16*)&vv;
        #pragma unroll
        for (int i = 0; i < 8; i++) {
            int hd = hd0 + i;
            Vts[hd * 136 + (tok ^ (((hd >> 3) & 3) << 3))] = pv[i];
        }
    }

    // QK^T direct from global (A/B fragments are contiguous 16B in [128][32] layout)
    f32x4 S[2][8];
    #pragma unroll
    for (int mt = 0; mt < 2; mt++)
        #pragma unroll
        for (int nt = 0; nt < 8; nt++) S[mt][nt] = (f32x4){0.f, 0.f, 0.f, 0.f};
    {
        short8 a[2];
        #pragma unroll
        for (int mt = 0; mt < 2; mt++) {
            int rq = w * 32 + mt * 16 + c;
            if (MUT) rq ^= 64;                   // swap halves for mutual attn
            a[mt] = *(const short8*)&qg[rq * 32 + q * 8];
        }
        #pragma unroll
        for (int nt = 0; nt < 8; nt++) {
            short8 b = *(const short8*)&kg[(nt * 16 + c) * 32 + q * 8];
            #pragma unroll
            for (int mt = 0; mt < 2; mt++) S[mt][nt] = mfma16(a[mt], b, S[mt][nt]);
        }
    }

    // region labels for analytic mask
    int rcnt[2][4], ccnt[8];
    #pragma unroll
    for (int mt = 0; mt < 2; mt++)
        #pragma unroll
        for (int r = 0; r < 4; r++) {
            int row = w * 32 + mt * 16 + q * 4 + r;
            rcnt[mt][r] = wincnt(win, MUT ? (row & 63) : row);
        }
    #pragma unroll
    for (int nt = 0; nt < 8; nt++) {
        int col = nt * 16 + c;
        ccnt[nt] = wincnt(win, MUT ? (col & 63) : col);
    }

    float mx[2][4];
    #pragma unroll
    for (int mt = 0; mt < 2; mt++)
      #pragma unroll
      for (int r = 0; r < 4; r++) mx[mt][r] = -3.0e38f;

    #pragma unroll
    for (int mt = 0; mt < 2; mt++)
      #pragma unroll
      for (int nt = 0; nt < 8; nt++) {
        float bv[4];
        if (!MUT) {
            int col = nt * 16 + c;
            us4 bb = *(const us4*)&biasrT[((size_t)(nh * 128 + col)) * 128
                                          + w * 32 + mt * 16 + q * 4];
            #pragma unroll
            for (int r = 0; r < 4; r++) bv[r] = bu2f(bb[r]);
        }
        bool valid = (w < 2) == (nt < 4);        // wave-uniform (MUT only)
        #pragma unroll
        for (int r = 0; r < 4; r++) {
            float s = S[mt][nt][r];
            if (MUT) {
                s = (rcnt[mt][r] == ccnt[nt]) ? s : s - 100.f;
                s = valid ? s : -30000.f;
            } else {
                s += bv[r];
                if (rcnt[mt][r] != ccnt[nt]) s -= 100.f;
            }
            S[mt][nt][r] = s;
            mx[mt][r] = fmaxf(mx[mt][r], s);
        }
      }
    #pragma unroll
    for (int mt = 0; mt < 2; mt++)
      #pragma unroll
      for (int r = 0; r < 4; r++) {
          float m = mx[mt][r];
          #pragma unroll
          for (int o = 1; o < 16; o <<= 1) m = fmaxf(m, __shfl_xor(m, o, 64));
          mx[mt][r] = m;
      }

    float sm[2][4] = {};
    #pragma unroll
    for (int mt = 0; mt < 2; mt++)
      #pragma unroll
      for (int nt = 0; nt < 8; nt++)
        #pragma unroll
        for (int r = 0; r < 4; r++) {
            float p = __expf(S[mt][nt][r] - mx[mt][r]);
            sm[mt][r] += p;
            Ps[(w * 32 + mt * 16 + q * 4 + r) * 136 + ((nt * 16 + c) ^ (q << 3))] = f2b(p);
        }
    #pragma unroll
    for (int mt = 0; mt < 2; mt++)
      #pragma unroll
      for (int r = 0; r < 4; r++) {
          float s = sm[mt][r];
          #pragma unroll
          for (int o = 1; o < 16; o <<= 1) s += __shfl_xor(s, o, 64);
          sm[mt][r] = s;
      }
    __syncthreads();                              // Vts + Ps ready

    f32x4 O[2][2];
    #pragma unroll
    for (int mt = 0; mt < 2; mt++)
        #pragma unroll
        for (int nt = 0; nt < 2; nt++) O[mt][nt] = (f32x4){0.f, 0.f, 0.f, 0.f};
    #pragma unroll
    for (int ks = 0; ks < 4; ks++) {
        short8 a[2];
        #pragma unroll
        for (int mt = 0; mt < 2; mt++) {
            int row = w * 32 + mt * 16 + c;
            int xr = ((c >> 2) & 3) << 3;         // = (row>>2)&3, matches writer q
            a[mt] = *(const short8*)&Ps[row * 136 + (ks * 32 + ((q << 3) ^ xr))];
        }
        #pragma unroll
        for (int nt = 0; nt < 2; nt++) {
            int hd = nt * 16 + c;
            int xv = ((hd >> 3) & 3) << 3;
            short8 b = *(const short8*)&Vts[hd * 136 + (ks * 32 + ((q << 3) ^ xv))];
            #pragma unroll
            for (int mt = 0; mt < 2; mt++) O[mt][nt] = mfma16(a[mt], b, O[mt][nt]);
        }
    }

    #pragma unroll
    for (int mt = 0; mt < 2; mt++)
      #pragma unroll
      for (int r = 0; r < 4; r++) {
          int row = w * 32 + mt * 16 + q * 4 + r;
          float inv = 1.f / sm[mt][r];
          #pragma unroll
          for (int nt = 0; nt < 2; nt++) {
              int col = nt * 16 + c;
              if (col < 30)
                  aout[((size_t)win * 128 + row) * 384 + (MUT ? 0 : 180) + nh * 30 + col] =
                      f2b(O[mt][nt][r] * inv);
          }
      }
}

// ---------------------------------------------------------------- launch
extern "C" void kernel_launch(void* const* d_in, const int* in_sizes, int n_in,
                              void* d_out, int out_size, void* d_ws, size_t ws_size,
                              hipStream_t stream)
{
    const float* x     = (const float*)d_in[0];
    const float* mask  = (const float*)d_in[1];
    const float* g1    = (const float*)d_in[2];
    const float* b1    = (const float*)d_in[3];
    const float* g2    = (const float*)d_in[4];
    const float* b2    = (const float*)d_in[5];
    const float* wqs   = (const float*)d_in[6];
    const float* bqs   = (const float*)d_in[7];
    const float* wqm   = (const float*)d_in[8];
    const float* bqm   = (const float*)d_in[9];
    const float* rpb   = (const float*)d_in[10];
    const float* posb  = (const float*)d_in[11];
    const float* wproj = (const float*)d_in[12];
    const float* bproj = (const float*)d_in[13];
    const float* w11   = (const float*)d_in[14];
    const float* bf11  = (const float*)d_in[15];
    const float* w12   = (const float*)d_in[16];
    const float* bf12  = (const float*)d_in[17];
    const float* w2    = (const float*)d_in[18];
    const float* bf2   = (const float*)d_in[19];
    const int*   rpi   = (const int*)d_in[20];
    float* out = (float*)d_out;
    (void)mask;   // mask is computed analytically in k_attn

    const size_t need = 265671168;
    if (ws_size < need) { fprintf(stderr, "[tmsa] ws too small: %zu < %zu\n", ws_size, need); return; }

    char* W = (char*)d_ws;
    bf16*  xw     = (bf16*)W;                              // [98304][192]
    bf16*  xwm    = (bf16*)(W + 37748736);                 // [98304][192]
    bf16*  attn   = (bf16*)(W + 75497472);                 // [98304][384]
    bf16*  qkv    = (bf16*)(W + 150994944);                // [3][4608][128][32]
    bf16*  biasrT = (bf16*)(W + 264241152);                // [6][128][128] bf16 (transposed)
    bf16*  Btqs   = (bf16*)(W + 264634368);                // [576][192]
    bf16*  Btqm   = (bf16*)(W + 264855552);                // [576][192]
    float* bbqs   = (float*)(W + 265076736);               // [576]
    float* bbqm   = (float*)(W + 265079040);               // [576]
    bf16*  Btproj = (bf16*)(W + 265081344);                // [192][384]
    bf16*  Btf11  = (bf16*)(W + 265228800);                // [384][192]
    bf16*  Btf12  = (bf16*)(W + 265376256);                // [384][192]
    bf16*  Btf2   = (bf16*)(W + 265523712);                // [192][384]

    k_rpbg<<<dim3(384), 256, 0, stream>>>(rpb, rpi, biasrT);
    k_pack_qkv<<<dim3(432), 256, 0, stream>>>(wqs, bqs, Btqs, bbqs);
    k_pack_qkv<<<dim3(432), 256, 0, stream>>>(wqm, bqm, Btqm, bbqm);
    k_pack<<<dim3(288), 256, 0, stream>>>(wproj, 180, 360, 384, Btproj);
    k_pack<<<dim3(288), 256, 0, stream>>>(w11,   360, 180, 192, Btf11);
    k_pack<<<dim3(288), 256, 0, stream>>>(w12,   360, 180, 192, Btf12);
    k_pack<<<dim3(288), 256, 0, stream>>>(w2,    180, 360, 384, Btf2);

    k_ln<true><<<dim3(24576), 256, 0, stream>>>(x, g1, b1, posb, xw, xwm);
    k_zpad<<<dim3(1152), 256, 0, stream>>>(attn);
    k_qkv<<<dim3(6912), 256, 0, stream>>>(xw, Btqs, bbqs, qkv);
    k_attn<false><<<dim3(4608), 256, 0, stream>>>(qkv, biasrT, attn);
    k_qkv<<<dim3(6912), 256, 0, stream>>>(xwm, Btqm, bbqm, qkv);
    k_attn<true><<<dim3(4608), 256, 0, stream>>>(qkv, biasrT, attn);
    k_proj<<<dim3(2304), 256, 0, stream>>>(attn, Btproj, bproj, x, out);
    k_ln<false><<<dim3(24576), 256, 0, stream>>>(out, g2, b2, nullptr, xw, nullptr);
    k_fc1<<<dim3(4608), 256, 0, stream>>>(xw, Btf11, bf11, Btf12, bf12, attn);
    k_fc2<<<dim3(2304), 256, 0, stream>>>(attn, Btf2, bf2, out);
}

// Round 9
// 609.981 us; speedup vs baseline: 1.4776x; 1.0032x over previous
//
#include <hip/hip_runtime.h>
#include <hip/hip_bf16.h>
#include <math.h>
#include <cstdio>

// TMSA block, fp32 I/O, bf16 MFMA internals, pre-packed bf16 weights.
// ws layout (bytes):
//   [0,          37748736)   xw    bf16 [98304][192]  (LN1 out; later LN2 out)
//   [37748736,  75497472)    xwm   bf16 [98304][192]  (xw + pos_bias)
//   [75497472,  150994944)   attn  bf16 [98304][384]  (attn out; later MLP hidden)
//   [150994944, 264241152)   qkv   bf16 [3][4608][128][32] (hd pad 30->32, q pre-scaled)
//   [264241152, 264634368)   biasrT bf16 [6][128 col][128 row] (transposed rpb gather)
//   [264634368, 265671168)   packed weights/biases (see offsets in launch)
// res (x + proj) lives in d_out (fp32), updated in-place by fc2.

typedef __hip_bfloat16 bf16;
typedef __attribute__((ext_vector_type(8))) short short8;
typedef __attribute__((ext_vector_type(4))) unsigned short us4;
typedef __attribute__((ext_vector_type(4))) float f32x4;

#define SCALE_F 0.18257418583505536f   // 30^-0.5
#define SZPE 18874368u                 // elems per qkv tensor: 4608*128*32

__device__ __forceinline__ bf16  f2b(float v){ return __float2bfloat16(v); }
__device__ __forceinline__ float bu2f(unsigned short u){
    union { unsigned int i; float f; } x; x.i = ((unsigned int)u) << 16; return x.f;
}
__device__ __forceinline__ us4 pack4(float a, float b, float c, float d){
    us4 r;
    bf16 t0 = f2b(a), t1 = f2b(b), t2 = f2b(c), t3 = f2b(d);
    r[0] = *(unsigned short*)&t0; r[1] = *(unsigned short*)&t1;
    r[2] = *(unsigned short*)&t2; r[3] = *(unsigned short*)&t3;
    return r;
}
__device__ __forceinline__ f32x4 mfma16(short8 a, short8 b, f32x4 c){
    return __builtin_amdgcn_mfma_f32_16x16x32_bf16(a, b, c, 0, 0, 0);
}

// async global->LDS, 16B per lane; LDS dest is wave-uniform base + lane*16.
__device__ __forceinline__ void gld16(const bf16* g, bf16* s){
    __builtin_amdgcn_global_load_lds(
        (const __attribute__((address_space(1))) unsigned int*)g,
        (__attribute__((address_space(3))) unsigned int*)s, 16, 0, 0);
}

// fast gelu with exact-erf semantics: A&S 7.1.26, |err(erf)| <= 1.5e-7
// (invisible under bf16 output rounding). ~13 VALU + 1 trans vs ~35 for erff.
__device__ __forceinline__ float gelu_erf(float x){
    float z  = fabsf(x) * 0.70710678118654752f;
    float t  = __builtin_amdgcn_rcpf(fmaf(0.3275911f, z, 1.f));
    float p  = fmaf(fmaf(fmaf(fmaf(1.061405429f, t, -1.453152027f),
                              t, 1.421413741f), t, -0.284496736f), t, 0.254829592f) * t;
    float e  = __expf(-z * z);
    float er = fmaf(-p, e, 1.f);          // erf(z), z >= 0
    er = (x >= 0.f) ? er : -er;
    return 0.5f * x * (1.f + er);
}

// XCD-aware bijective block swizzle: consecutive work ids land on one XCD.
// All GEMM grids are multiples of 8.
__device__ __forceinline__ int xswz(){
    return (blockIdx.x & 7) * ((int)gridDim.x >> 3) + ((int)blockIdx.x >> 3);
}

// Swin region label for (window, token): mask[win][i][j] == 0 iff label_i == label_j.
__device__ __forceinline__ int wincnt(int win, int tok){
    int d = (win >> 8) * 2 + (tok >> 6);
    int h = ((win >> 4) & 15) * 8 + ((tok >> 3) & 7);
    int w = (win & 15) * 8 + (tok & 7);
    int rd = (d >= 4) + (d >= 5);
    int rh = (h >= 120) + (h >= 124);
    int rw = (w >= 120) + (w >= 124);
    return (rd * 3 + rh) * 3 + rw;
}

// window-reverse + roll: token row -> fp32 base offset (elements) in [D][H][W][C]
__device__ __forceinline__ size_t wrev_base(int row){
    int win = row >> 7, tok = row & 127;
    int wd = win >> 8, wh = (win >> 4) & 15, ww = win & 15;
    int td = tok >> 6, th = (tok >> 3) & 7, tw = tok & 7;
    int d = wd * 2 + td + 1; if (d >= 6) d -= 6;
    int h = (wh * 8 + th + 4) & 127;
    int wcol = (ww * 8 + tw + 4) & 127;
    return ((size_t)((d * 128 + h) * 128 + wcol)) * 180;
}

// ---------------------------------------------------------------- weight packing
__global__ __launch_bounds__(256) void k_pack_qkv(const float* __restrict__ w,
                                                  const float* __restrict__ bias,
                                                  bf16* __restrict__ Bt,
                                                  float* __restrict__ bb)
{
    int idx = blockIdx.x * 256 + threadIdx.x;      // < 110592
    int n = idx / 192, k = idx - n * 192;
    int three = n / 192;
    int rem = n - three * 192, nh = rem >> 5, hdp = rem & 31;
    int srcc = three * 180 + nh * 30 + hdp;
    float v = 0.f;
    if (hdp < 30 && k < 180) v = w[(size_t)k * 540 + srcc];
    if (three == 0) v *= SCALE_F;
    Bt[(size_t)n * 192 + k] = f2b(v);
    if (k == 0) bb[n] = (hdp < 30) ? ((three == 0 ? SCALE_F : 1.f) * bias[srcc]) : 0.f;
}

// generic: Bt[n][k] (NP x KP) = w[k][n] (K x NW), zero-padded.
__global__ __launch_bounds__(256) void k_pack(const float* __restrict__ w,
                                              int NW, int K, int KP,
                                              bf16* __restrict__ Bt)
{
    int idx = blockIdx.x * 256 + threadIdx.x;
    int n = idx / KP, k = idx - n * KP;
    float v = (n < NW && k < K) ? w[(size_t)k * NW + n] : 0.f;
    Bt[idx] = f2b(v);
}

// ---------------------------------------------------------------- rpb gather (transposed, bf16)
__global__ __launch_bounds__(256) void k_rpbg(const float* __restrict__ rpb,
                                              const int* __restrict__ rpi,
                                              bf16* __restrict__ biasrT)
{
    int n = blockIdx.x * 256 + threadIdx.x;       // < 98304
    int nh = n >> 14, rc = n & 16383;
    int row = rc >> 7, col = rc & 127;
    biasrT[((size_t)nh * 128 + col) * 128 + row] = f2b(rpb[rpi[rc] * 6 + nh]);
}

// zero attn pad cols 360..383 (stride-384 buffer)
__global__ __launch_bounds__(256) void k_zpad(bf16* __restrict__ attn)
{
    int gi = blockIdx.x * 256 + threadIdx.x;      // < 294912
    int row = gi / 3, part = gi - row * 3;
    *(uint4*)&attn[(size_t)row * 384 + 360 + part * 8] = make_uint4(0u,0u,0u,0u);
}

// ---------------------------------------------------------------- LayerNorm (vectorized)
template<bool ROLL_PB>
__global__ __launch_bounds__(256) void k_ln(const float* __restrict__ x,
                                            const float* __restrict__ g,
                                            const float* __restrict__ b,
                                            const float* __restrict__ pb,
                                            bf16* __restrict__ xw,
                                            bf16* __restrict__ xwm)
{
    int row  = blockIdx.x * 4 + (threadIdx.x >> 6);
    int lane = threadIdx.x & 63;
    const float* src = ROLL_PB ? (x + wrev_base(row)) : (x + (size_t)row * 180);
    float4 v = make_float4(0.f, 0.f, 0.f, 0.f);
    if (lane < 45) v = *(const float4*)&src[lane * 4];
    float s  = v.x + v.y + v.z + v.w;
    float ss = v.x*v.x + v.y*v.y + v.z*v.z + v.w*v.w;
    #pragma unroll
    for (int o = 32; o > 0; o >>= 1) { s += __shfl_xor(s, o, 64); ss += __shfl_xor(ss, o, 64); }
    float mean = s * (1.f/180.f);
    float var  = ss * (1.f/180.f) - mean*mean;
    float rstd = rsqrtf(var + 1e-5f);

    bf16* dst = xw + (size_t)row * 192;
    float4 y = make_float4(0.f, 0.f, 0.f, 0.f);
    if (lane < 45) {
        float4 gv = *(const float4*)&g[lane * 4];
        float4 bv = *(const float4*)&b[lane * 4];
        y.x = (v.x - mean) * rstd * gv.x + bv.x;
        y.y = (v.y - mean) * rstd * gv.y + bv.y;
        y.z = (v.z - mean) * rstd * gv.z + bv.z;
        y.w = (v.w - mean) * rstd * gv.w + bv.w;
        *(us4*)&dst[lane * 4] = pack4(y.x, y.y, y.z, y.w);
    } else if (lane < 48) {
        *(us4*)&dst[lane * 4] = (us4){0, 0, 0, 0};
    }
    if (ROLL_PB) {
        bf16* dm = xwm + (size_t)row * 192;
        if (lane < 45) {
            const float* pbr = pb + (size_t)(row & 63) * 180;
            float4 pv = *(const float4*)&pbr[lane * 4];
            *(us4*)&dm[lane * 4] = pack4(y.x + pv.x, y.y + pv.y, y.z + pv.z, y.w + pv.w);
        } else if (lane < 48) {
            *(us4*)&dm[lane * 4] = (us4){0, 0, 0, 0};
        }
    }
}

// ---------------------------------------------------------------- MFMA GEMM core v7
// C[256 x 64] tile of A[M x KP](bf16) @ Bt[N][KP](bf16, pre-transposed).
// Proven v3 staging (global_load_lds w=16, chunk-swizzled content, 2 barriers
// per K-step) with M-tile 256: 10-12 gld16 + 2 barriers amortize over 32-64
// MFMA (2x the 128-tile), halving per-output barrier/stall cost (m93 lever).
// Wave w owns rows w*64..w*64+63 (4 mt sub-tiles).
template<int KP, bool DUAL>
__device__ __forceinline__ void mm4(const bf16* __restrict__ A,
                                    const bf16* __restrict__ Bt1,
                                    const bf16* __restrict__ Bt2,
                                    bf16* As, bf16* Bs1, bf16* Bs2,
                                    int m0, int n0,
                                    f32x4 (&acc1)[4][4], f32x4 (&acc2)[4][4])
{
    const int tid = threadIdx.x;
    const int w = tid >> 6, l = tid & 63, q = l >> 4, c = l & 15;
    const int lr = l >> 3, lj = l & 7;
    const int swz = ((lj ^ lr) << 3);             // pre-swizzled source chunk (elems)
    #pragma unroll
    for (int ks = 0; ks < KP / 64; ks++) {
        #pragma unroll
        for (int e = 0; e < 8; e++) {             // A: 256 rows, 8 rows per wave-load
            int m = (e * 4 + w) * 8 + lr;
            gld16(&A[(size_t)(m0 + m) * KP + ks * 64 + swz], &As[((e * 4 + w) * 8) * 64]);
        }
        #pragma unroll
        for (int e = 0; e < 2; e++) {             // B: 64 rows
            int n = (e * 4 + w) * 8 + lr;
            gld16(&Bt1[(size_t)(n0 + n) * KP + ks * 64 + swz], &Bs1[((e * 4 + w) * 8) * 64]);
            if (DUAL)
                gld16(&Bt2[(size_t)(n0 + n) * KP + ks * 64 + swz], &Bs2[((e * 4 + w) * 8) * 64]);
        }
        __syncthreads();                          // drains vmcnt (gld writes landed)
        #pragma unroll
        for (int k32 = 0; k32 < 2; k32++) {
            int koff = (((k32 * 4 + q) ^ (c & 7)) << 3);
            short8 a[4];
            #pragma unroll
            for (int mt = 0; mt < 4; mt++)
                a[mt] = *(const short8*)&As[(w * 64 + mt * 16 + c) * 64 + koff];
            #pragma unroll
            for (int nt = 0; nt < 4; nt++) {
                short8 b1 = *(const short8*)&Bs1[(nt * 16 + c) * 64 + koff];
                #pragma unroll
                for (int mt = 0; mt < 4; mt++) acc1[mt][nt] = mfma16(a[mt], b1, acc1[mt][nt]);
                if (DUAL) {
                    short8 b2 = *(const short8*)&Bs2[(nt * 16 + c) * 64 + koff];
                    #pragma unroll
                    for (int mt = 0; mt < 4; mt++) acc2[mt][nt] = mfma16(a[mt], b2, acc2[mt][nt]);
                }
            }
        }
        __syncthreads();
    }
}

// epilogue LDS roundtrip swizzle (bf16 path): chunk ^= (row>>2)&7.
__device__ __forceinline__ int cs_idx(int row, int colt){
    return row * 64 + ((((colt >> 3) ^ ((row >> 2) & 7)) << 3) | (colt & 7));
}

// qkv GEMM: KP=192, N=576 packed; vectorized scatter to qkv via LDS roundtrip.
__global__ __launch_bounds__(256) void k_qkv(const bf16* __restrict__ A,
                                             const bf16* __restrict__ Bt,
                                             const float* __restrict__ bb,
                                             bf16* __restrict__ outq)
{
    __shared__ __align__(16) bf16 As[256 * 64];   // 32768 B (also epilogue Cs)
    __shared__ __align__(16) bf16 Bs[64 * 64];    // 8192 B
    int bid = xswz();                             // 3456 = 384 * 9, n-fastest
    int n0 = (bid % 9) * 64, m0 = (bid / 9) * 256;
    f32x4 a1[4][4] = {}, a2[4][4];
    mm4<192, false>(A, Bt, nullptr, As, Bs, nullptr, m0, n0, a1, a2);

    int tid = threadIdx.x, w = tid >> 6, l = tid & 63, q = l >> 4, c = l & 15;
    bf16* Cs = As;
    #pragma unroll
    for (int mt = 0; mt < 4; mt++)
      #pragma unroll
      for (int nt = 0; nt < 4; nt++)
        #pragma unroll
        for (int r = 0; r < 4; r++) {
            int row = w * 64 + mt * 16 + q * 4 + r;
            int colt = nt * 16 + c;
            Cs[cs_idx(row, colt)] = f2b(a1[mt][nt][r] + bb[n0 + colt]);
        }
    __syncthreads();
    #pragma unroll
    for (int e = 0; e < 8; e++) {
        int gi = e * 256 + tid;                   // < 2048
        int row = gi >> 3, j = gi & 7, c8 = j * 8;
        int col = n0 + c8;
        int three = col / 192, rem = col - three * 192;
        int nh = rem >> 5, hdp = rem & 31;
        int gr = m0 + row, win = gr >> 7, rw = gr & 127;
        bf16* dst = outq + (size_t)three * SZPE + ((size_t)(win * 6 + nh) * 128 + rw) * 32 + hdp;
        *(uint4*)dst = *(const uint4*)&Cs[row * 64 + ((j ^ ((row >> 2) & 7)) << 3)];
    }
}

// proj GEMM: KP=384 (attn stride), N pad 192; window-reverse + roll + residual -> d_out.
// Epilogue: fp32 LDS roundtrip in four 64-row strips ([64][76] pad), then
// float4-coalesced xin read + res write (16 lanes cover 256B/row).
__global__ __launch_bounds__(256) void k_proj(const bf16* __restrict__ A,
                                              const bf16* __restrict__ Bt,
                                              const float* __restrict__ bias,
                                              const float* __restrict__ xin,
                                              float* __restrict__ res)
{
    __shared__ __align__(16) char smem[40960];
    bf16*  As = (bf16*)smem;                      // 32768 B
    bf16*  Bs = (bf16*)(smem + 32768);            // 8192 B
    float* Cs = (float*)smem;                     // [64][76] = 19456 B per strip
    int bid = xswz();                             // 1152 = 384 * 3
    int n0 = (bid % 3) * 64, m0 = (bid / 3) * 256;
    f32x4 a1[4][4] = {}, a2[4][4];
    mm4<384, false>(A, Bt, nullptr, As, Bs, nullptr, m0, n0, a1, a2);

    int tid = threadIdx.x, w = tid >> 6, l = tid & 63, q = l >> 4, c = l & 15;
    #pragma unroll
    for (int h = 0; h < 4; h++) {                 // strip h = rows h*64..+63 (wave h's)
        __syncthreads();                          // prev readers of Cs/As done
        if (w == h) {
            #pragma unroll
            for (int mt = 0; mt < 4; mt++)
              #pragma unroll
              for (int nt = 0; nt < 4; nt++)
                #pragma unroll
                for (int r = 0; r < 4; r++) {
                    int rl = mt * 16 + q * 4 + r;          // 0..63
                    Cs[rl * 76 + nt * 16 + c] = a1[mt][nt][r];
                }
        }
        __syncthreads();
        #pragma unroll
        for (int e = 0; e < 4; e++) {
            int slot = e * 256 + tid;             // < 1024: 64 rows x 16 quads
            int rl = slot >> 4, cq = slot & 15;
            int col = n0 + cq * 4;
            if (col < 180) {
                size_t base = wrev_base(m0 + h * 64 + rl) + col;
                float4 xi = *(const float4*)&xin[base];
                float4 bi = *(const float4*)&bias[col];
                const float* cp = &Cs[rl * 76 + cq * 4];
                float4 o;
                o.x = xi.x + cp[0] + bi.x;
                o.y = xi.y + cp[1] + bi.y;
                o.z = xi.z + cp[2] + bi.z;
                o.w = xi.w + cp[3] + bi.w;
                *(float4*)&res[base] = o;
            }
        }
    }
}

// fc1: KP=192, N pad 384 dual; gelu(x1)*x2 -> hid [98304][384] via LDS roundtrip.
__global__ __launch_bounds__(256) void k_fc1(const bf16* __restrict__ A,
                                             const bf16* __restrict__ Bt1,
                                             const float* __restrict__ bb1,
                                             const bf16* __restrict__ Bt2,
                                             const float* __restrict__ bb2,
                                             bf16* __restrict__ hid)
{
    __shared__ __align__(16) bf16 As[256 * 64];   // 32768 B (also epilogue Cs)
    __shared__ __align__(16) bf16 Bs1[64 * 64];
    __shared__ __align__(16) bf16 Bs2[64 * 64];   // total 49152 B
    int bid = xswz();                             // 2304 = 384 * 6
    int n0 = (bid % 6) * 64, m0 = (bid / 6) * 256;
    f32x4 a1[4][4] = {}, a2[4][4] = {};
    mm4<192, true>(A, Bt1, Bt2, As, Bs1, Bs2, m0, n0, a1, a2);

    int tid = threadIdx.x, w = tid >> 6, l = tid & 63, q = l >> 4, c = l & 15;
    bf16* Cs = As;
    #pragma unroll
    for (int mt = 0; mt < 4; mt++)
      #pragma unroll
      for (int nt = 0; nt < 4; nt++)
        #pragma unroll
        for (int r = 0; r < 4; r++) {
            int row = w * 64 + mt * 16 + q * 4 + r;
            int colt = nt * 16 + c;
            int col = n0 + colt;
            float hv = 0.f;
            if (col < 360)
                hv = gelu_erf(a1[mt][nt][r] + bb1[col]) * (a2[mt][nt][r] + bb2[col]);
            Cs[cs_idx(row, colt)] = f2b(hv);
        }
    __syncthreads();
    #pragma unroll
    for (int e = 0; e < 8; e++) {
        int gi = e * 256 + tid;                   // < 2048
        int row = gi >> 3, j = gi & 7, c8 = j * 8;
        *(uint4*)&hid[(size_t)(m0 + row) * 384 + n0 + c8] =
            *(const uint4*)&Cs[row * 64 + ((j ^ ((row >> 2) & 7)) << 3)];
    }
}

// fc2: KP=384 (hid stride), N pad 192; out += hid@w2 + b (in-place fp32).
// Same fp32-roundtrip + float4 RMW epilogue as proj (rows linear here).
__global__ __launch_bounds__(256) void k_fc2(const bf16* __restrict__ A,
                                             const bf16* __restrict__ Bt,
                                             const float* __restrict__ bias,
                                             float* __restrict__ out)
{
    __shared__ __align__(16) char smem[40960];
    bf16*  As = (bf16*)smem;
    bf16*  Bs = (bf16*)(smem + 32768);
    float* Cs = (float*)smem;                     // [64][76]
    int bid = xswz();                             // 1152
    int n0 = (bid % 3) * 64, m0 = (bid / 3) * 256;
    f32x4 a1[4][4] = {}, a2[4][4];
    mm4<384, false>(A, Bt, nullptr, As, Bs, nullptr, m0, n0, a1, a2);

    int tid = threadIdx.x, w = tid >> 6, l = tid & 63, q = l >> 4, c = l & 15;
    #pragma unroll
    for (int h = 0; h < 4; h++) {
        __syncthreads();
        if (w == h) {
            #pragma unroll
            for (int mt = 0; mt < 4; mt++)
              #pragma unroll
              for (int nt = 0; nt < 4; nt++)
                #pragma unroll
                for (int r = 0; r < 4; r++) {
                    int rl = mt * 16 + q * 4 + r;
                    Cs[rl * 76 + nt * 16 + c] = a1[mt][nt][r];
                }
        }
        __syncthreads();
        #pragma unroll
        for (int e = 0; e < 4; e++) {
            int slot = e * 256 + tid;
            int rl = slot >> 4, cq = slot & 15;
            int col = n0 + cq * 4;
            if (col < 180) {
                size_t idx = (size_t)(m0 + h * 64 + rl) * 180 + col;
                float4 ov = *(const float4*)&out[idx];
                float4 bi = *(const float4*)&bias[col];
                const float* cp = &Cs[rl * 76 + cq * 4];
                ov.x += cp[0] + bi.x;
                ov.y += cp[1] + bi.y;
                ov.z += cp[2] + bi.z;
                ov.w += cp[3] + bi.w;
                *(float4*)&out[idx] = ov;
            }
        }
    }
}

// ---------------------------------------------------------------- MFMA attention v2
// Q/K fragments loaded direct from global; mask analytic; bias from transposed
// bf16 table; Vts/Ps XOR-swizzled; LDS 43520B -> 3 blocks/CU.
template<bool MUT>
__global__ __launch_bounds__(256) void k_attn(const bf16* __restrict__ qkv,
                                              const bf16* __restrict__ biasrT,
                                              bf16* __restrict__ aout)
{
    __shared__ __align__(16) bf16 Vts[32 * 136];
    __shared__ __align__(16) bf16 Ps[128 * 136];

    int wh = blockIdx.x, win = wh / 6, nh = wh - win * 6;
    const bf16* qg = qkv + (size_t)wh * 4096;
    const bf16* kg = qg + (size_t)SZPE;
    const bf16* vg = qg + 2 * (size_t)SZPE;
    int tid = threadIdx.x, w = tid >> 6, l = tid & 63, q = l >> 4, c = l & 15;

    // stage V transposed (swizzled): 2 x uint4 global loads per thread
    #pragma unroll
    for (int e = 0; e < 2; e++) {
        int base = (e * 256 + tid) * 8;          // < 4096
        int tok = base >> 5, hd0 = base & 31;
        uint4 vv = *(const uint4*)&vg[base];
        const bf16* pv = (const bf16*)&vv;
        #pragma unroll
        for (int i = 0; i < 8; i++) {
            int hd = hd0 + i;
            Vts[hd * 136 + (tok ^ (((hd >> 3) & 3) << 3))] = pv[i];
        }
    }

    // QK^T direct from global (A/B fragments are contiguous 16B in [128][32] layout)
    f32x4 S[2][8];
    #pragma unroll
    for (int mt = 0; mt < 2; mt++)
        #pragma unroll
        for (int nt = 0; nt < 8; nt++) S[mt][nt] = (f32x4){0.f, 0.f, 0.f, 0.f};
    {
        short8 a[2];
        #pragma unroll
        for (int mt = 0; mt < 2; mt++) {
            int rq = w * 32 + mt * 16 + c;
            if (MUT) rq ^= 64;                   // swap halves for mutual attn
            a[mt] = *(const short8*)&qg[rq * 32 + q * 8];
        }
        #pragma unroll
        for (int nt = 0; nt < 8; nt++) {
            short8 b = *(const short8*)&kg[(nt * 16 + c) * 32 + q * 8];
            #pragma unroll
            for (int mt = 0; mt < 2; mt++) S[mt][nt] = mfma16(a[mt], b, S[mt][nt]);
        }
    }

    // region labels for analytic mask
    int rcnt[2][4], ccnt[8];
    #pragma unroll
    for (int mt = 0; mt < 2; mt++)
        #pragma unroll
        for (int r = 0; r < 4; r++) {
            int row = w * 32 + mt * 16 + q * 4 + r;
            rcnt[mt][r] = wincnt(win, MUT ? (row & 63) : row);
        }
    #pragma unroll
    for (int nt = 0; nt < 8; nt++) {
        int col = nt * 16 + c;
        ccnt[nt] = wincnt(win, MUT ? (col & 63) : col);
    }

    float mx[2][4];
    #pragma unroll
    for (int mt = 0; mt < 2; mt++)
      #pragma unroll
      for (int r = 0; r < 4; r++) mx[mt][r] = -3.0e38f;

    #pragma unroll
    for (int mt = 0; mt < 2; mt++)
      #pragma unroll
      for (int nt = 0; nt < 8; nt++) {
        float bv[4];
        if (!MUT) {
            int col = nt * 16 + c;
            us4 bb = *(const us4*)&biasrT[((size_t)(nh * 128 + col)) * 128
                                          + w * 32 + mt * 16 + q * 4];
            #pragma unroll
            for (int r = 0; r < 4; r++) bv[r] = bu2f(bb[r]);
        }
        bool valid = (w < 2) == (nt < 4);        // wave-uniform (MUT only)
        #pragma unroll
        for (int r = 0; r < 4; r++) {
            float s = S[mt][nt][r];
            if (MUT) {
                s = (rcnt[mt][r] == ccnt[nt]) ? s : s - 100.f;
                s = valid ? s : -30000.f;
            } else {
                s += bv[r];
                if (rcnt[mt][r] != ccnt[nt]) s -= 100.f;
            }
            S[mt][nt][r] = s;
            mx[mt][r] = fmaxf(mx[mt][r], s);
        }
      }
    #pragma unroll
    for (int mt = 0; mt < 2; mt++)
      #pragma unroll
      for (int r = 0; r < 4; r++) {
          float m = mx[mt][r];
          #pragma unroll
          for (int o = 1; o < 16; o <<= 1) m = fmaxf(m, __shfl_xor(m, o, 64));
          mx[mt][r] = m;
      }

    float sm[2][4] = {};
    #pragma unroll
    for (int mt = 0; mt < 2; mt++)
      #pragma unroll
      for (int nt = 0; nt < 8; nt++)
        #pragma unroll
        for (int r = 0; r < 4; r++) {
            float p = __expf(S[mt][nt][r] - mx[mt][r]);
            sm[mt][r] += p;
            Ps[(w * 32 + mt * 16 + q * 4 + r) * 136 + ((nt * 16 + c) ^ (q << 3))] = f2b(p);
        }
    #pragma unroll
    for (int mt = 0; mt < 2; mt++)
      #pragma unroll
      for (int r = 0; r < 4; r++) {
          float s = sm[mt][r];
          #pragma unroll
          for (int o = 1; o < 16; o <<= 1) s += __shfl_xor(s, o, 64);
          sm[mt][r] = s;
      }
    __syncthreads();                              // Vts + Ps ready

    f32x4 O[2][2];
    #pragma unroll
    for (int mt = 0; mt < 2; mt++)
        #pragma unroll
        for (int nt = 0; nt < 2; nt++) O[mt][nt] = (f32x4){0.f, 0.f, 0.f, 0.f};
    #pragma unroll
    for (int ks = 0; ks < 4; ks++) {
        short8 a[2];
        #pragma unroll
        for (int mt = 0; mt < 2; mt++) {
            int row = w * 32 + mt * 16 + c;
            int xr = ((c >> 2) & 3) << 3;         // = (row>>2)&3, matches writer q
            a[mt] = *(const short8*)&Ps[row * 136 + (ks * 32 + ((q << 3) ^ xr))];
        }
        #pragma unroll
        for (int nt = 0; nt < 2; nt++) {
            int hd = nt * 16 + c;
            int xv = ((hd >> 3) & 3) << 3;
            short8 b = *(const short8*)&Vts[hd * 136 + (ks * 32 + ((q << 3) ^ xv))];
            #pragma unroll
            for (int mt = 0; mt < 2; mt++) O[mt][nt] = mfma16(a[mt], b, O[mt][nt]);
        }
    }

    #pragma unroll
    for (int mt = 0; mt < 2; mt++)
      #pragma unroll
      for (int r = 0; r < 4; r++) {
          int row = w * 32 + mt * 16 + q * 4 + r;
          float inv = 1.f / sm[mt][r];
          #pragma unroll
          for (int nt = 0; nt < 2; nt++) {
              int col = nt * 16 + c;
              if (col < 30)
                  aout[((size_t)win * 128 + row) * 384 + (MUT ? 0 : 180) + nh * 30 + col] =
                      f2b(O[mt][nt][r] * inv);
          }
      }
}

// ---------------------------------------------------------------- launch
extern "C" void kernel_launch(void* const* d_in, const int* in_sizes, int n_in,
                              void* d_out, int out_size, void* d_ws, size_t ws_size,
                              hipStream_t stream)
{
    const float* x     = (const float*)d_in[0];
    const float* mask  = (const float*)d_in[1];
    const float* g1    = (const float*)d_in[2];
    const float* b1    = (const float*)d_in[3];
    const float* g2    = (const float*)d_in[4];
    const float* b2    = (const float*)d_in[5];
    const float* wqs   = (const float*)d_in[6];
    const float* bqs   = (const float*)d_in[7];
    const float* wqm   = (const float*)d_in[8];
    const float* bqm   = (const float*)d_in[9];
    const float* rpb   = (const float*)d_in[10];
    const float* posb  = (const float*)d_in[11];
    const float* wproj = (const float*)d_in[12];
    const float* bproj = (const float*)d_in[13];
    const float* w11   = (const float*)d_in[14];
    const float* bf11  = (const float*)d_in[15];
    const float* w12   = (const float*)d_in[16];
    const float* bf12  = (const float*)d_in[17];
    const float* w2    = (const float*)d_in[18];
    const float* bf2   = (const float*)d_in[19];
    const int*   rpi   = (const int*)d_in[20];
    float* out = (float*)d_out;
    (void)mask;   // mask is computed analytically in k_attn

    const size_t need = 265671168;
    if (ws_size < need) { fprintf(stderr, "[tmsa] ws too small: %zu < %zu\n", ws_size, need); return; }

    char* W = (char*)d_ws;
    bf16*  xw     = (bf16*)W;                              // [98304][192]
    bf16*  xwm    = (bf16*)(W + 37748736);                 // [98304][192]
    bf16*  attn   = (bf16*)(W + 75497472);                 // [98304][384]
    bf16*  qkv    = (bf16*)(W + 150994944);                // [3][4608][128][32]
    bf16*  biasrT = (bf16*)(W + 264241152);                // [6][128][128] bf16 (transposed)
    bf16*  Btqs   = (bf16*)(W + 264634368);                // [576][192]
    bf16*  Btqm   = (bf16*)(W + 264855552);                // [576][192]
    float* bbqs   = (float*)(W + 265076736);               // [576]
    float* bbqm   = (float*)(W + 265079040);               // [576]
    bf16*  Btproj = (bf16*)(W + 265081344);                // [192][384]
    bf16*  Btf11  = (bf16*)(W + 265228800);                // [384][192]
    bf16*  Btf12  = (bf16*)(W + 265376256);                // [384][192]
    bf16*  Btf2   = (bf16*)(W + 265523712);                // [192][384]

    k_rpbg<<<dim3(384), 256, 0, stream>>>(rpb, rpi, biasrT);
    k_pack_qkv<<<dim3(432), 256, 0, stream>>>(wqs, bqs, Btqs, bbqs);
    k_pack_qkv<<<dim3(432), 256, 0, stream>>>(wqm, bqm, Btqm, bbqm);
    k_pack<<<dim3(288), 256, 0, stream>>>(wproj, 180, 360, 384, Btproj);
    k_pack<<<dim3(288), 256, 0, stream>>>(w11,   360, 180, 192, Btf11);
    k_pack<<<dim3(288), 256, 0, stream>>>(w12,   360, 180, 192, Btf12);
    k_pack<<<dim3(288), 256, 0, stream>>>(w2,    180, 360, 384, Btf2);

    k_ln<true><<<dim3(24576), 256, 0, stream>>>(x, g1, b1, posb, xw, xwm);
    k_zpad<<<dim3(1152), 256, 0, stream>>>(attn);
    k_qkv<<<dim3(3456), 256, 0, stream>>>(xw, Btqs, bbqs, qkv);
    k_attn<false><<<dim3(4608), 256, 0, stream>>>(qkv, biasrT, attn);
    k_qkv<<<dim3(3456), 256, 0, stream>>>(xwm, Btqm, bbqm, qkv);
    k_attn<true><<<dim3(4608), 256, 0, stream>>>(qkv, biasrT, attn);
    k_proj<<<dim3(1152), 256, 0, stream>>>(attn, Btproj, bproj, x, out);
    k_ln<false><<<dim3(24576), 256, 0, stream>>>(out, g2, b2, nullptr, xw, nullptr);
    k_fc1<<<dim3(2304), 256, 0, stream>>>(xw, Btf11, bf11, Btf12, bf12, attn);
    k_fc2<<<dim3(1152), 256, 0, stream>>>(attn, Btf2, bf2, out);
}

// Round 10
// 580.583 us; speedup vs baseline: 1.5525x; 1.0506x over previous
//
#include <hip/hip_runtime.h>
#include <hip/hip_bf16.h>
#include <math.h>
#include <cstdio>

// TMSA block, fp32 I/O, bf16 MFMA internals, pre-packed bf16 weights.
// ws layout (bytes):
//   [0,          37748736)   xw    bf16 [98304][192]  (LN1 out; later LN2 out)
//   [37748736,  75497472)    xwm   bf16 [98304][192]  (xw + pos_bias)
//   [75497472,  150994944)   attn  bf16 [98304][384]  (attn out; later MLP hidden)
//   [150994944, 264241152)   qkv   bf16 [3][4608][128][32] (hd pad 30->32, q pre-scaled)
//   [264241152, 264634368)   biasrT bf16 [6][128 col][128 row] (transposed rpb gather)
//   [264634368, 265671168)   packed weights/biases (see offsets in launch)
// res (x + proj) lives in d_out (fp32), updated in-place by fc2.

typedef __hip_bfloat16 bf16;
typedef __attribute__((ext_vector_type(8))) short short8;
typedef __attribute__((ext_vector_type(4))) unsigned short us4;
typedef __attribute__((ext_vector_type(4))) float f32x4;

#define SCALE_F 0.18257418583505536f   // 30^-0.5
#define SZPE 18874368u                 // elems per qkv tensor: 4608*128*32

__device__ __forceinline__ bf16  f2b(float v){ return __float2bfloat16(v); }
__device__ __forceinline__ float bu2f(unsigned short u){
    union { unsigned int i; float f; } x; x.i = ((unsigned int)u) << 16; return x.f;
}
__device__ __forceinline__ us4 pack4(float a, float b, float c, float d){
    us4 r;
    bf16 t0 = f2b(a), t1 = f2b(b), t2 = f2b(c), t3 = f2b(d);
    r[0] = *(unsigned short*)&t0; r[1] = *(unsigned short*)&t1;
    r[2] = *(unsigned short*)&t2; r[3] = *(unsigned short*)&t3;
    return r;
}
__device__ __forceinline__ f32x4 mfma16(short8 a, short8 b, f32x4 c){
    return __builtin_amdgcn_mfma_f32_16x16x32_bf16(a, b, c, 0, 0, 0);
}

// async global->LDS, 16B per lane; LDS dest is wave-uniform base + lane*16.
__device__ __forceinline__ void gld16(const bf16* g, bf16* s){
    __builtin_amdgcn_global_load_lds(
        (const __attribute__((address_space(1))) unsigned int*)g,
        (__attribute__((address_space(3))) unsigned int*)s, 16, 0, 0);
}

// fast gelu with exact-erf semantics: A&S 7.1.26, |err(erf)| <= 1.5e-7
__device__ __forceinline__ float gelu_erf(float x){
    float z  = fabsf(x) * 0.70710678118654752f;
    float t  = __builtin_amdgcn_rcpf(fmaf(0.3275911f, z, 1.f));
    float p  = fmaf(fmaf(fmaf(fmaf(1.061405429f, t, -1.453152027f),
                              t, 1.421413741f), t, -0.284496736f), t, 0.254829592f) * t;
    float e  = __expf(-z * z);
    float er = fmaf(-p, e, 1.f);          // erf(z), z >= 0
    er = (x >= 0.f) ? er : -er;
    return 0.5f * x * (1.f + er);
}

// XCD-aware bijective block swizzle: consecutive work ids land on one XCD.
__device__ __forceinline__ int xswz(){
    return (blockIdx.x & 7) * ((int)gridDim.x >> 3) + ((int)blockIdx.x >> 3);
}

// Swin region label for (window, token): mask[win][i][j] == 0 iff label_i == label_j.
__device__ __forceinline__ int wincnt(int win, int tok){
    int d = (win >> 8) * 2 + (tok >> 6);
    int h = ((win >> 4) & 15) * 8 + ((tok >> 3) & 7);
    int w = (win & 15) * 8 + (tok & 7);
    int rd = (d >= 4) + (d >= 5);
    int rh = (h >= 120) + (h >= 124);
    int rw = (w >= 120) + (w >= 124);
    return (rd * 3 + rh) * 3 + rw;
}

// window-reverse + roll: token row -> fp32 base offset (elements) in [D][H][W][C]
__device__ __forceinline__ size_t wrev_base(int row){
    int win = row >> 7, tok = row & 127;
    int wd = win >> 8, wh = (win >> 4) & 15, ww = win & 15;
    int td = tok >> 6, th = (tok >> 3) & 7, tw = tok & 7;
    int d = wd * 2 + td + 1; if (d >= 6) d -= 6;
    int h = (wh * 8 + th + 4) & 127;
    int wcol = (ww * 8 + tw + 4) & 127;
    return ((size_t)((d * 128 + h) * 128 + wcol)) * 180;
}

// ---------------------------------------------------------------- merged prep
// One launch replaces: rpbg(384) + pack_qkv x2(432 ea) + pack x4(288 ea) + zpad(1152).
__device__ __forceinline__ void prep_pack_qkv(int idx, const float* w, const float* bias,
                                              bf16* Bt, float* bb)
{
    int n = idx / 192, k = idx - n * 192;
    int three = n / 192;
    int rem = n - three * 192, nh = rem >> 5, hdp = rem & 31;
    int srcc = three * 180 + nh * 30 + hdp;
    float v = 0.f;
    if (hdp < 30 && k < 180) v = w[(size_t)k * 540 + srcc];
    if (three == 0) v *= SCALE_F;
    Bt[(size_t)n * 192 + k] = f2b(v);
    if (k == 0) bb[n] = (hdp < 30) ? ((three == 0 ? SCALE_F : 1.f) * bias[srcc]) : 0.f;
}
__device__ __forceinline__ void prep_pack(int idx, const float* w,
                                          int NW, int K, int KP, bf16* Bt)
{
    int n = idx / KP, k = idx - n * KP;
    float v = (n < NW && k < K) ? w[(size_t)k * NW + n] : 0.f;
    Bt[idx] = f2b(v);
}
__global__ __launch_bounds__(256) void k_prep(const float* __restrict__ rpb,
                                              const int* __restrict__ rpi,
                                              bf16* __restrict__ biasrT,
                                              const float* __restrict__ wqs,
                                              const float* __restrict__ bqs,
                                              bf16* __restrict__ Btqs,
                                              float* __restrict__ bbqs,
                                              const float* __restrict__ wqm,
                                              const float* __restrict__ bqm,
                                              bf16* __restrict__ Btqm,
                                              float* __restrict__ bbqm,
                                              const float* __restrict__ wproj,
                                              bf16* __restrict__ Btproj,
                                              const float* __restrict__ w11,
                                              bf16* __restrict__ Btf11,
                                              const float* __restrict__ w12,
                                              bf16* __restrict__ Btf12,
                                              const float* __restrict__ w2,
                                              bf16* __restrict__ Btf2,
                                              bf16* __restrict__ attn)
{
    int bid = blockIdx.x, tid = threadIdx.x;
    if (bid < 384) {                               // rpb gather (transposed, bf16)
        int n = bid * 256 + tid;                   // < 98304
        int nh = n >> 14, rc = n & 16383;
        int row = rc >> 7, col = rc & 127;
        biasrT[((size_t)nh * 128 + col) * 128 + row] = f2b(rpb[rpi[rc] * 6 + nh]);
    } else if (bid < 816) {
        prep_pack_qkv((bid - 384) * 256 + tid, wqs, bqs, Btqs, bbqs);
    } else if (bid < 1248) {
        prep_pack_qkv((bid - 816) * 256 + tid, wqm, bqm, Btqm, bbqm);
    } else if (bid < 1536) {
        prep_pack((bid - 1248) * 256 + tid, wproj, 180, 360, 384, Btproj);
    } else if (bid < 1824) {
        prep_pack((bid - 1536) * 256 + tid, w11, 360, 180, 192, Btf11);
    } else if (bid < 2112) {
        prep_pack((bid - 1824) * 256 + tid, w12, 360, 180, 192, Btf12);
    } else if (bid < 2400) {
        prep_pack((bid - 2112) * 256 + tid, w2, 180, 360, 384, Btf2);
    } else {                                       // zero attn pad cols 360..383
        int gi = (bid - 2400) * 256 + tid;         // < 294912
        int row = gi / 3, part = gi - row * 3;
        *(uint4*)&attn[(size_t)row * 384 + 360 + part * 8] = make_uint4(0u,0u,0u,0u);
    }
}

// ---------------------------------------------------------------- LayerNorm (vectorized)
template<bool ROLL_PB>
__global__ __launch_bounds__(256) void k_ln(const float* __restrict__ x,
                                            const float* __restrict__ g,
                                            const float* __restrict__ b,
                                            const float* __restrict__ pb,
                                            bf16* __restrict__ xw,
                                            bf16* __restrict__ xwm)
{
    int row  = blockIdx.x * 4 + (threadIdx.x >> 6);
    int lane = threadIdx.x & 63;
    const float* src = ROLL_PB ? (x + wrev_base(row)) : (x + (size_t)row * 180);
    float4 v = make_float4(0.f, 0.f, 0.f, 0.f);
    if (lane < 45) v = *(const float4*)&src[lane * 4];
    float s  = v.x + v.y + v.z + v.w;
    float ss = v.x*v.x + v.y*v.y + v.z*v.z + v.w*v.w;
    #pragma unroll
    for (int o = 32; o > 0; o >>= 1) { s += __shfl_xor(s, o, 64); ss += __shfl_xor(ss, o, 64); }
    float mean = s * (1.f/180.f);
    float var  = ss * (1.f/180.f) - mean*mean;
    float rstd = rsqrtf(var + 1e-5f);

    bf16* dst = xw + (size_t)row * 192;
    float4 y = make_float4(0.f, 0.f, 0.f, 0.f);
    if (lane < 45) {
        float4 gv = *(const float4*)&g[lane * 4];
        float4 bv = *(const float4*)&b[lane * 4];
        y.x = (v.x - mean) * rstd * gv.x + bv.x;
        y.y = (v.y - mean) * rstd * gv.y + bv.y;
        y.z = (v.z - mean) * rstd * gv.z + bv.z;
        y.w = (v.w - mean) * rstd * gv.w + bv.w;
        *(us4*)&dst[lane * 4] = pack4(y.x, y.y, y.z, y.w);
    } else if (lane < 48) {
        *(us4*)&dst[lane * 4] = (us4){0, 0, 0, 0};
    }
    if (ROLL_PB) {
        bf16* dm = xwm + (size_t)row * 192;
        if (lane < 45) {
            const float* pbr = pb + (size_t)(row & 63) * 180;
            float4 pv = *(const float4*)&pbr[lane * 4];
            *(us4*)&dm[lane * 4] = pack4(y.x + pv.x, y.y + pv.y, y.z + pv.z, y.w + pv.w);
        } else if (lane < 48) {
            *(us4*)&dm[lane * 4] = (us4){0, 0, 0, 0};
        }
    }
}

// ---------------------------------------------------------------- MFMA GEMM core v3 (proven)
// C[128 x 64] tile of A[M x KP](bf16) @ Bt[N][KP](bf16, pre-transposed).
// global_load_lds width=16; LDS linear [rows][64], content chunk-swizzled
// via pre-swizzled global source; ds_read applies same XOR. 2 barriers/K-step.
template<int KP, bool DUAL>
__device__ __forceinline__ void mm2(const bf16* __restrict__ A,
                                    const bf16* __restrict__ Bt1,
                                    const bf16* __restrict__ Bt2,
                                    bf16* As, bf16* Bs1, bf16* Bs2,
                                    int m0, int n0,
                                    f32x4 (&acc1)[2][4], f32x4 (&acc2)[2][4])
{
    const int tid = threadIdx.x;
    const int w = tid >> 6, l = tid & 63, q = l >> 4, c = l & 15;
    const int lr = l >> 3, lj = l & 7;
    const int swz = ((lj ^ lr) << 3);             // pre-swizzled source chunk (elems)
    #pragma unroll
    for (int ks = 0; ks < KP / 64; ks++) {
        #pragma unroll
        for (int e = 0; e < 4; e++) {             // A: 128 rows, 8 rows per wave-load
            int m = (e * 4 + w) * 8 + lr;
            gld16(&A[(size_t)(m0 + m) * KP + ks * 64 + swz], &As[((e * 4 + w) * 8) * 64]);
        }
        #pragma unroll
        for (int e = 0; e < 2; e++) {             // B: 64 rows
            int n = (e * 4 + w) * 8 + lr;
            gld16(&Bt1[(size_t)(n0 + n) * KP + ks * 64 + swz], &Bs1[((e * 4 + w) * 8) * 64]);
            if (DUAL)
                gld16(&Bt2[(size_t)(n0 + n) * KP + ks * 64 + swz], &Bs2[((e * 4 + w) * 8) * 64]);
        }
        __syncthreads();                          // drains vmcnt (gld writes landed)
        #pragma unroll
        for (int k32 = 0; k32 < 2; k32++) {
            int koff = (((k32 * 4 + q) ^ (c & 7)) << 3);
            short8 a[2];
            #pragma unroll
            for (int mt = 0; mt < 2; mt++)
                a[mt] = *(const short8*)&As[(w * 32 + mt * 16 + c) * 64 + koff];
            #pragma unroll
            for (int nt = 0; nt < 4; nt++) {
                short8 b1 = *(const short8*)&Bs1[(nt * 16 + c) * 64 + koff];
                #pragma unroll
                for (int mt = 0; mt < 2; mt++) acc1[mt][nt] = mfma16(a[mt], b1, acc1[mt][nt]);
                if (DUAL) {
                    short8 b2 = *(const short8*)&Bs2[(nt * 16 + c) * 64 + koff];
                    #pragma unroll
                    for (int mt = 0; mt < 2; mt++) acc2[mt][nt] = mfma16(a[mt], b2, acc2[mt][nt]);
                }
            }
        }
        __syncthreads();
    }
}

// epilogue LDS roundtrip swizzle (bf16 path): chunk ^= (row>>2)&7.
__device__ __forceinline__ int cs_idx(int row, int colt){
    return row * 64 + ((((colt >> 3) ^ ((row >> 2) & 7)) << 3) | (colt & 7));
}

// qkv GEMM: KP=192, N=576 packed; vectorized scatter to qkv via LDS roundtrip.
__global__ __launch_bounds__(256) void k_qkv(const bf16* __restrict__ A,
                                             const bf16* __restrict__ Bt,
                                             const float* __restrict__ bb,
                                             bf16* __restrict__ outq)
{
    __shared__ __align__(16) bf16 As[128 * 64];
    __shared__ __align__(16) bf16 Bs[64 * 64];
    int bid = xswz();                             // 6912 = 768 * 9, n-fastest
    int n0 = (bid % 9) * 64, m0 = (bid / 9) * 128;
    f32x4 a1[2][4] = {}, a2[2][4];
    mm2<192, false>(A, Bt, nullptr, As, Bs, nullptr, m0, n0, a1, a2);

    int tid = threadIdx.x, w = tid >> 6, l = tid & 63, q = l >> 4, c = l & 15;
    bf16* Cs = As;
    #pragma unroll
    for (int mt = 0; mt < 2; mt++)
      #pragma unroll
      for (int nt = 0; nt < 4; nt++)
        #pragma unroll
        for (int r = 0; r < 4; r++) {
            int row = w * 32 + mt * 16 + q * 4 + r;
            int colt = nt * 16 + c;
            Cs[cs_idx(row, colt)] = f2b(a1[mt][nt][r] + bb[n0 + colt]);
        }
    __syncthreads();
    int win = m0 >> 7;
    #pragma unroll
    for (int e = 0; e < 4; e++) {
        int gi = e * 256 + tid;                   // < 1024
        int row = gi >> 3, j = gi & 7, c8 = j * 8;
        int col = n0 + c8;
        int three = col / 192, rem = col - three * 192;
        int nh = rem >> 5, hdp = rem & 31;
        bf16* dst = outq + (size_t)three * SZPE + ((size_t)(win * 6 + nh) * 128 + row) * 32 + hdp;
        *(uint4*)dst = *(const uint4*)&Cs[row * 64 + ((j ^ ((row >> 2) & 7)) << 3)];
    }
}

// proj GEMM: KP=384 (attn stride), N pad 192; window-reverse + roll + residual -> d_out.
__global__ __launch_bounds__(256) void k_proj(const bf16* __restrict__ A,
                                              const bf16* __restrict__ Bt,
                                              const float* __restrict__ bias,
                                              const float* __restrict__ xin,
                                              float* __restrict__ res)
{
    __shared__ __align__(16) char smem[24576];
    bf16*  As = (bf16*)smem;                      // 16384 B
    bf16*  Bs = (bf16*)(smem + 16384);            // 8192 B
    float* Cs = (float*)smem;                     // [64][76] = 19456 B per half
    int bid = xswz();                             // 2304 = 768 * 3
    int n0 = (bid % 3) * 64, m0 = (bid / 3) * 128;
    f32x4 a1[2][4] = {}, a2[2][4];
    mm2<384, false>(A, Bt, nullptr, As, Bs, nullptr, m0, n0, a1, a2);

    int tid = threadIdx.x, w = tid >> 6, l = tid & 63, q = l >> 4, c = l & 15;
    #pragma unroll
    for (int h = 0; h < 2; h++) {
        __syncthreads();                          // prev readers of Cs/As done
        if ((w >> 1) == h) {                      // waves 2h,2h+1 own rows h*64..+63
            #pragma unroll
            for (int mt = 0; mt < 2; mt++)
              #pragma unroll
              for (int nt = 0; nt < 4; nt++)
                #pragma unroll
                for (int r = 0; r < 4; r++) {
                    int rl = (w & 1) * 32 + mt * 16 + q * 4 + r;   // 0..63
                    Cs[rl * 76 + nt * 16 + c] = a1[mt][nt][r];
                }
        }
        __syncthreads();
        #pragma unroll
        for (int e = 0; e < 4; e++) {
            int slot = e * 256 + tid;             // < 1024: 64 rows x 16 quads
            int rl = slot >> 4, cq = slot & 15;
            int col = n0 + cq * 4;
            if (col < 180) {
                size_t base = wrev_base(m0 + h * 64 + rl) + col;
                float4 xi = *(const float4*)&xin[base];
                float4 bi = *(const float4*)&bias[col];
                const float* cp = &Cs[rl * 76 + cq * 4];
                float4 o;
                o.x = xi.x + cp[0] + bi.x;
                o.y = xi.y + cp[1] + bi.y;
                o.z = xi.z + cp[2] + bi.z;
                o.w = xi.w + cp[3] + bi.w;
                *(float4*)&res[base] = o;
            }
        }
    }
}

// fc1: KP=192, N pad 384 dual; gelu(x1)*x2 -> hid [98304][384] via LDS roundtrip.
__global__ __launch_bounds__(256) void k_fc1(const bf16* __restrict__ A,
                                             const bf16* __restrict__ Bt1,
                                             const float* __restrict__ bb1,
                                             const bf16* __restrict__ Bt2,
                                             const float* __restrict__ bb2,
                                             bf16* __restrict__ hid)
{
    __shared__ __align__(16) bf16 As[128 * 64];
    __shared__ __align__(16) bf16 Bs1[64 * 64];
    __shared__ __align__(16) bf16 Bs2[64 * 64];
    int bid = xswz();                             // 4608 = 768 * 6
    int n0 = (bid % 6) * 64, m0 = (bid / 6) * 128;
    f32x4 a1[2][4] = {}, a2[2][4] = {};
    mm2<192, true>(A, Bt1, Bt2, As, Bs1, Bs2, m0, n0, a1, a2);

    int tid = threadIdx.x, w = tid >> 6, l = tid & 63, q = l >> 4, c = l & 15;
    bf16* Cs = As;
    #pragma unroll
    for (int mt = 0; mt < 2; mt++)
      #pragma unroll
      for (int nt = 0; nt < 4; nt++)
        #pragma unroll
        for (int r = 0; r < 4; r++) {
            int row = w * 32 + mt * 16 + q * 4 + r;
            int colt = nt * 16 + c;
            int col = n0 + colt;
            float hv = 0.f;
            if (col < 360)
                hv = gelu_erf(a1[mt][nt][r] + bb1[col]) * (a2[mt][nt][r] + bb2[col]);
            Cs[cs_idx(row, colt)] = f2b(hv);
        }
    __syncthreads();
    #pragma unroll
    for (int e = 0; e < 4; e++) {
        int gi = e * 256 + tid;
        int row = gi >> 3, j = gi & 7, c8 = j * 8;
        *(uint4*)&hid[(size_t)(m0 + row) * 384 + n0 + c8] =
            *(const uint4*)&Cs[row * 64 + ((j ^ ((row >> 2) & 7)) << 3)];
    }
}

// fc2: KP=384 (hid stride), N pad 192; out += hid@w2 + b (in-place fp32).
__global__ __launch_bounds__(256) void k_fc2(const bf16* __restrict__ A,
                                             const bf16* __restrict__ Bt,
                                             const float* __restrict__ bias,
                                             float* __restrict__ out)
{
    __shared__ __align__(16) char smem[24576];
    bf16*  As = (bf16*)smem;
    bf16*  Bs = (bf16*)(smem + 16384);
    float* Cs = (float*)smem;                     // [64][76]
    int bid = xswz();                             // 2304
    int n0 = (bid % 3) * 64, m0 = (bid / 3) * 128;
    f32x4 a1[2][4] = {}, a2[2][4];
    mm2<384, false>(A, Bt, nullptr, As, Bs, nullptr, m0, n0, a1, a2);

    int tid = threadIdx.x, w = tid >> 6, l = tid & 63, q = l >> 4, c = l & 15;
    #pragma unroll
    for (int h = 0; h < 2; h++) {
        __syncthreads();
        if ((w >> 1) == h) {
            #pragma unroll
            for (int mt = 0; mt < 2; mt++)
              #pragma unroll
              for (int nt = 0; nt < 4; nt++)
                #pragma unroll
                for (int r = 0; r < 4; r++) {
                    int rl = (w & 1) * 32 + mt * 16 + q * 4 + r;
                    Cs[rl * 76 + nt * 16 + c] = a1[mt][nt][r];
                }
        }
        __syncthreads();
        #pragma unroll
        for (int e = 0; e < 4; e++) {
            int slot = e * 256 + tid;
            int rl = slot >> 4, cq = slot & 15;
            int col = n0 + cq * 4;
            if (col < 180) {
                size_t idx = (size_t)(m0 + h * 64 + rl) * 180 + col;
                float4 ov = *(const float4*)&out[idx];
                float4 bi = *(const float4*)&bias[col];
                const float* cp = &Cs[rl * 76 + cq * 4];
                ov.x += cp[0] + bi.x;
                ov.y += cp[1] + bi.y;
                ov.z += cp[2] + bi.z;
                ov.w += cp[3] + bi.w;
                *(float4*)&out[idx] = ov;
            }
        }
    }
}

// ---------------------------------------------------------------- MFMA attention v3
// Q/K fragments direct from global; mask analytic; bias from transposed bf16 table;
// Vts/Ps XOR-swizzled. MUT: block-diagonal -- each wave computes only its valid
// 64-col half (wave-uniform), halving QK^T, softmax, and PV work. Math identical
// (dropped terms were exp(-30000)==0).
template<bool MUT>
__global__ __launch_bounds__(256) void k_attn(const bf16* __restrict__ qkv,
                                              const bf16* __restrict__ biasrT,
                                              bf16* __restrict__ aout)
{
    __shared__ __align__(16) bf16 Vts[32 * 136];
    __shared__ __align__(16) bf16 Ps[128 * 136];

    int wh = blockIdx.x, win = wh / 6, nh = wh - win * 6;
    const bf16* qg = qkv + (size_t)wh * 4096;
    const bf16* kg = qg + (size_t)SZPE;
    const bf16* vg = qg + 2 * (size_t)SZPE;
    int tid = threadIdx.x, w = tid >> 6, l = tid & 63, q = l >> 4, c = l & 15;

    constexpr int NT = MUT ? 4 : 8;               // col-tiles computed per wave
    const int colbase = MUT ? ((w < 2) ? 0 : 64) : 0;   // wave-uniform

    // stage V transposed (swizzled): 2 x uint4 global loads per thread
    #pragma unroll
    for (int e = 0; e < 2; e++) {
        int base = (e * 256 + tid) * 8;          // < 4096
        int tok = base >> 5, hd0 = base & 31;
        uint4 vv = *(const uint4*)&vg[base];
        const bf16* pv = (const bf16*)&vv;
        #pragma unroll
        for (int i = 0; i < 8; i++) {
            int hd = hd0 + i;
            Vts[hd * 136 + (tok ^ (((hd >> 3) & 3) << 3))] = pv[i];
        }
    }

    // QK^T direct from global (fragments are contiguous 16B in [128][32] layout)
    f32x4 S[2][NT];
    #pragma unroll
    for (int mt = 0; mt < 2; mt++)
        #pragma unroll
        for (int nt = 0; nt < NT; nt++) S[mt][nt] = (f32x4){0.f, 0.f, 0.f, 0.f};
    {
        short8 a[2];
        #pragma unroll
        for (int mt = 0; mt < 2; mt++) {
            int rq = w * 32 + mt * 16 + c;
            if (MUT) rq ^= 64;                   // swap halves for mutual attn
            a[mt] = *(const short8*)&qg[rq * 32 + q * 8];
        }
        #pragma unroll
        for (int nt = 0; nt < NT; nt++) {
            short8 b = *(const short8*)&kg[(colbase + nt * 16 + c) * 32 + q * 8];
            #pragma unroll
            for (int mt = 0; mt < 2; mt++) S[mt][nt] = mfma16(a[mt], b, S[mt][nt]);
        }
    }

    // region labels for analytic mask
    int rcnt[2][4], ccnt[NT];
    #pragma unroll
    for (int mt = 0; mt < 2; mt++)
        #pragma unroll
        for (int r = 0; r < 4; r++) {
            int row = w * 32 + mt * 16 + q * 4 + r;
            rcnt[mt][r] = wincnt(win, MUT ? (row & 63) : row);
        }
    #pragma unroll
    for (int nt = 0; nt < NT; nt++) {
        int col = colbase + nt * 16 + c;
        ccnt[nt] = wincnt(win, MUT ? (col & 63) : col);
    }

    float mx[2][4];
    #pragma unroll
    for (int mt = 0; mt < 2; mt++)
      #pragma unroll
      for (int r = 0; r < 4; r++) mx[mt][r] = -3.0e38f;

    #pragma unroll
    for (int mt = 0; mt < 2; mt++)
      #pragma unroll
      for (int nt = 0; nt < NT; nt++) {
        float bv[4];
        if (!MUT) {
            int col = nt * 16 + c;
            us4 bb = *(const us4*)&biasrT[((size_t)(nh * 128 + col)) * 128
                                          + w * 32 + mt * 16 + q * 4];
            #pragma unroll
            for (int r = 0; r < 4; r++) bv[r] = bu2f(bb[r]);
        }
        #pragma unroll
        for (int r = 0; r < 4; r++) {
            float s = S[mt][nt][r];
            if (MUT) {
                s = (rcnt[mt][r] == ccnt[nt]) ? s : s - 100.f;
            } else {
                s += bv[r];
                if (rcnt[mt][r] != ccnt[nt]) s -= 100.f;
            }
            S[mt][nt][r] = s;
            mx[mt][r] = fmaxf(mx[mt][r], s);
        }
      }
    #pragma unroll
    for (int mt = 0; mt < 2; mt++)
      #pragma unroll
      for (int r = 0; r < 4; r++) {
          float m = mx[mt][r];
          #pragma unroll
          for (int o = 1; o < 16; o <<= 1) m = fmaxf(m, __shfl_xor(m, o, 64));
          mx[mt][r] = m;
      }

    float sm[2][4] = {};
    #pragma unroll
    for (int mt = 0; mt < 2; mt++)
      #pragma unroll
      for (int nt = 0; nt < NT; nt++)
        #pragma unroll
        for (int r = 0; r < 4; r++) {
            float p = __expf(S[mt][nt][r] - mx[mt][r]);
            sm[mt][r] += p;
            Ps[(w * 32 + mt * 16 + q * 4 + r) * 136 + ((colbase + nt * 16 + c) ^ (q << 3))] = f2b(p);
        }
    #pragma unroll
    for (int mt = 0; mt < 2; mt++)
      #pragma unroll
      for (int r = 0; r < 4; r++) {
          float s = sm[mt][r];
          #pragma unroll
          for (int o = 1; o < 16; o <<= 1) s += __shfl_xor(s, o, 64);
          sm[mt][r] = s;
      }
    __syncthreads();                              // Vts + Ps ready

    f32x4 O[2][2];
    #pragma unroll
    for (int mt = 0; mt < 2; mt++)
        #pragma unroll
        for (int nt = 0; nt < 2; nt++) O[mt][nt] = (f32x4){0.f, 0.f, 0.f, 0.f};
    #pragma unroll
    for (int ksr = 0; ksr < (MUT ? 2 : 4); ksr++) {
        int ks = MUT ? ((colbase >> 5) + ksr) : ksr;
        short8 a[2];
        #pragma unroll
        for (int mt = 0; mt < 2; mt++) {
            int row = w * 32 + mt * 16 + c;
            int xr = ((c >> 2) & 3) << 3;         // = (row>>2)&3, matches writer q
            a[mt] = *(const short8*)&Ps[row * 136 + (ks * 32 + ((q << 3) ^ xr))];
        }
        #pragma unroll
        for (int nt = 0; nt < 2; nt++) {
            int hd = nt * 16 + c;
            int xv = ((hd >> 3) & 3) << 3;
            short8 b = *(const short8*)&Vts[hd * 136 + (ks * 32 + ((q << 3) ^ xv))];
            #pragma unroll
            for (int mt = 0; mt < 2; mt++) O[mt][nt] = mfma16(a[mt], b, O[mt][nt]);
        }
    }

    #pragma unroll
    for (int mt = 0; mt < 2; mt++)
      #pragma unroll
      for (int r = 0; r < 4; r++) {
          int row = w * 32 + mt * 16 + q * 4 + r;
          float inv = 1.f / sm[mt][r];
          #pragma unroll
          for (int nt = 0; nt < 2; nt++) {
              int col = nt * 16 + c;
              if (col < 30)
                  aout[((size_t)win * 128 + row) * 384 + (MUT ? 0 : 180) + nh * 30 + col] =
                      f2b(O[mt][nt][r] * inv);
          }
      }
}

// ---------------------------------------------------------------- launch
extern "C" void kernel_launch(void* const* d_in, const int* in_sizes, int n_in,
                              void* d_out, int out_size, void* d_ws, size_t ws_size,
                              hipStream_t stream)
{
    const float* x     = (const float*)d_in[0];
    const float* mask  = (const float*)d_in[1];
    const float* g1    = (const float*)d_in[2];
    const float* b1    = (const float*)d_in[3];
    const float* g2    = (const float*)d_in[4];
    const float* b2    = (const float*)d_in[5];
    const float* wqs   = (const float*)d_in[6];
    const float* bqs   = (const float*)d_in[7];
    const float* wqm   = (const float*)d_in[8];
    const float* bqm   = (const float*)d_in[9];
    const float* rpb   = (const float*)d_in[10];
    const float* posb  = (const float*)d_in[11];
    const float* wproj = (const float*)d_in[12];
    const float* bproj = (const float*)d_in[13];
    const float* w11   = (const float*)d_in[14];
    const float* bf11  = (const float*)d_in[15];
    const float* w12   = (const float*)d_in[16];
    const float* bf12  = (const float*)d_in[17];
    const float* w2    = (const float*)d_in[18];
    const float* bf2   = (const float*)d_in[19];
    const int*   rpi   = (const int*)d_in[20];
    float* out = (float*)d_out;
    (void)mask;   // mask is computed analytically in k_attn

    const size_t need = 265671168;
    if (ws_size < need) { fprintf(stderr, "[tmsa] ws too small: %zu < %zu\n", ws_size, need); return; }

    char* W = (char*)d_ws;
    bf16*  xw     = (bf16*)W;                              // [98304][192]
    bf16*  xwm    = (bf16*)(W + 37748736);                 // [98304][192]
    bf16*  attn   = (bf16*)(W + 75497472);                 // [98304][384]
    bf16*  qkv    = (bf16*)(W + 150994944);                // [3][4608][128][32]
    bf16*  biasrT = (bf16*)(W + 264241152);                // [6][128][128] bf16 (transposed)
    bf16*  Btqs   = (bf16*)(W + 264634368);                // [576][192]
    bf16*  Btqm   = (bf16*)(W + 264855552);                // [576][192]
    float* bbqs   = (float*)(W + 265076736);               // [576]
    float* bbqm   = (float*)(W + 265079040);               // [576]
    bf16*  Btproj = (bf16*)(W + 265081344);                // [192][384]
    bf16*  Btf11  = (bf16*)(W + 265228800);                // [384][192]
    bf16*  Btf12  = (bf16*)(W + 265376256);                // [384][192]
    bf16*  Btf2   = (bf16*)(W + 265523712);                // [192][384]

    k_prep<<<dim3(3552), 256, 0, stream>>>(rpb, rpi, biasrT,
                                           wqs, bqs, Btqs, bbqs,
                                           wqm, bqm, Btqm, bbqm,
                                           wproj, Btproj, w11, Btf11,
                                           w12, Btf12, w2, Btf2, attn);

    k_ln<true><<<dim3(24576), 256, 0, stream>>>(x, g1, b1, posb, xw, xwm);
    k_qkv<<<dim3(6912), 256, 0, stream>>>(xw, Btqs, bbqs, qkv);
    k_attn<false><<<dim3(4608), 256, 0, stream>>>(qkv, biasrT, attn);
    k_qkv<<<dim3(6912), 256, 0, stream>>>(xwm, Btqm, bbqm, qkv);
    k_attn<true><<<dim3(4608), 256, 0, stream>>>(qkv, biasrT, attn);
    k_proj<<<dim3(2304), 256, 0, stream>>>(attn, Btproj, bproj, x, out);
    k_ln<false><<<dim3(24576), 256, 0, stream>>>(out, g2, b2, nullptr, xw, nullptr);
    k_fc1<<<dim3(4608), 256, 0, stream>>>(xw, Btf11, bf11, Btf12, bf12, attn);
    k_fc2<<<dim3(2304), 256, 0, stream>>>(attn, Btf2, bf2, out);
}

// Round 11
// 556.190 us; speedup vs baseline: 1.6205x; 1.0439x over previous
//
#include <hip/hip_runtime.h>
#include <hip/hip_bf16.h>
#include <math.h>
#include <cstdio>

// TMSA block, fp32 I/O, bf16 MFMA internals, pre-packed bf16 weights.
// ws layout (bytes):
//   [0,          37748736)   xw    bf16 [98304][192]  (LN1 out; later LN2 out)
//   [37748736,  37896192)    pbW   fp32 [64][576]     (pos_bias @ Wqm, q pre-scaled)
//   [75497472,  150994944)   attn  bf16 [98304][384]  (attn out; later MLP hidden)
//   [150994944, 264241152)   qkv   bf16 [3][4608][128][32] (hd pad 30->32, q pre-scaled)
//   [264241152, 264634368)   biasrT bf16 [6][128 col][128 row] (transposed rpb gather)
//   [264634368, 265671168)   packed weights/biases (see offsets in launch)
// res (x + proj) lives in d_out (fp32), updated in-place by fc2.

typedef __hip_bfloat16 bf16;
typedef __attribute__((ext_vector_type(8))) short short8;
typedef __attribute__((ext_vector_type(4))) unsigned short us4;
typedef __attribute__((ext_vector_type(4))) float f32x4;

#define SCALE_F 0.18257418583505536f   // 30^-0.5
#define SZPE 18874368u                 // elems per qkv tensor: 4608*128*32

__device__ __forceinline__ bf16  f2b(float v){ return __float2bfloat16(v); }
__device__ __forceinline__ float bu2f(unsigned short u){
    union { unsigned int i; float f; } x; x.i = ((unsigned int)u) << 16; return x.f;
}
__device__ __forceinline__ us4 pack4(float a, float b, float c, float d){
    us4 r;
    bf16 t0 = f2b(a), t1 = f2b(b), t2 = f2b(c), t3 = f2b(d);
    r[0] = *(unsigned short*)&t0; r[1] = *(unsigned short*)&t1;
    r[2] = *(unsigned short*)&t2; r[3] = *(unsigned short*)&t3;
    return r;
}
__device__ __forceinline__ f32x4 mfma16(short8 a, short8 b, f32x4 c){
    return __builtin_amdgcn_mfma_f32_16x16x32_bf16(a, b, c, 0, 0, 0);
}

// async global->LDS, 16B per lane; LDS dest is wave-uniform base + lane*16.
__device__ __forceinline__ void gld16(const bf16* g, bf16* s){
    __builtin_amdgcn_global_load_lds(
        (const __attribute__((address_space(1))) unsigned int*)g,
        (__attribute__((address_space(3))) unsigned int*)s, 16, 0, 0);
}

// fast gelu with exact-erf semantics: A&S 7.1.26, |err(erf)| <= 1.5e-7
__device__ __forceinline__ float gelu_erf(float x){
    float z  = fabsf(x) * 0.70710678118654752f;
    float t  = __builtin_amdgcn_rcpf(fmaf(0.3275911f, z, 1.f));
    float p  = fmaf(fmaf(fmaf(fmaf(1.061405429f, t, -1.453152027f),
                              t, 1.421413741f), t, -0.284496736f), t, 0.254829592f) * t;
    float e  = __expf(-z * z);
    float er = fmaf(-p, e, 1.f);          // erf(z), z >= 0
    er = (x >= 0.f) ? er : -er;
    return 0.5f * x * (1.f + er);
}

// XCD-aware bijective block swizzle: consecutive work ids land on one XCD.
__device__ __forceinline__ int xswz(){
    return (blockIdx.x & 7) * ((int)gridDim.x >> 3) + ((int)blockIdx.x >> 3);
}

// Swin region label for (window, token): mask[win][i][j] == 0 iff label_i == label_j.
__device__ __forceinline__ int wincnt(int win, int tok){
    int d = (win >> 8) * 2 + (tok >> 6);
    int h = ((win >> 4) & 15) * 8 + ((tok >> 3) & 7);
    int w = (win & 15) * 8 + (tok & 7);
    int rd = (d >= 4) + (d >= 5);
    int rh = (h >= 120) + (h >= 124);
    int rw = (w >= 120) + (w >= 124);
    return (rd * 3 + rh) * 3 + rw;
}

// window-reverse + roll: token row -> fp32 base offset (elements) in [D][H][W][C]
__device__ __forceinline__ size_t wrev_base(int row){
    int win = row >> 7, tok = row & 127;
    int wd = win >> 8, wh = (win >> 4) & 15, ww = win & 15;
    int td = tok >> 6, th = (tok >> 3) & 7, tw = tok & 7;
    int d = wd * 2 + td + 1; if (d >= 6) d -= 6;
    int h = (wh * 8 + th + 4) & 127;
    int wcol = (ww * 8 + tw + 4) & 127;
    return ((size_t)((d * 128 + h) * 128 + wcol)) * 180;
}

// ---------------------------------------------------------------- merged prep
// One launch: rpbg + pack_qkv x2 + pack x4 + zpad + pbW (pos_bias @ Wqm).
__device__ __forceinline__ void prep_pack_qkv(int idx, const float* w, const float* bias,
                                              bf16* Bt, float* bb)
{
    int n = idx / 192, k = idx - n * 192;
    int three = n / 192;
    int rem = n - three * 192, nh = rem >> 5, hdp = rem & 31;
    int srcc = three * 180 + nh * 30 + hdp;
    float v = 0.f;
    if (hdp < 30 && k < 180) v = w[(size_t)k * 540 + srcc];
    if (three == 0) v *= SCALE_F;
    Bt[(size_t)n * 192 + k] = f2b(v);
    if (k == 0) bb[n] = (hdp < 30) ? ((three == 0 ? SCALE_F : 1.f) * bias[srcc]) : 0.f;
}
__device__ __forceinline__ void prep_pack(int idx, const float* w,
                                          int NW, int K, int KP, bf16* Bt)
{
    int n = idx / KP, k = idx - n * KP;
    float v = (n < NW && k < K) ? w[(size_t)k * NW + n] : 0.f;
    Bt[idx] = f2b(v);
}
__global__ __launch_bounds__(256) void k_prep(const float* __restrict__ rpb,
                                              const int* __restrict__ rpi,
                                              bf16* __restrict__ biasrT,
                                              const float* __restrict__ wqs,
                                              const float* __restrict__ bqs,
                                              bf16* __restrict__ Btqs,
                                              float* __restrict__ bbqs,
                                              const float* __restrict__ wqm,
                                              const float* __restrict__ bqm,
                                              bf16* __restrict__ Btqm,
                                              float* __restrict__ bbqm,
                                              const float* __restrict__ wproj,
                                              bf16* __restrict__ Btproj,
                                              const float* __restrict__ w11,
                                              bf16* __restrict__ Btf11,
                                              const float* __restrict__ w12,
                                              bf16* __restrict__ Btf12,
                                              const float* __restrict__ w2,
                                              bf16* __restrict__ Btf2,
                                              bf16* __restrict__ attn,
                                              const float* __restrict__ posb,
                                              float* __restrict__ pbW)
{
    int bid = blockIdx.x, tid = threadIdx.x;
    if (bid < 384) {                               // rpb gather (transposed, bf16)
        int n = bid * 256 + tid;                   // < 98304
        int nh = n >> 14, rc = n & 16383;
        int row = rc >> 7, col = rc & 127;
        biasrT[((size_t)nh * 128 + col) * 128 + row] = f2b(rpb[rpi[rc] * 6 + nh]);
    } else if (bid < 816) {
        prep_pack_qkv((bid - 384) * 256 + tid, wqs, bqs, Btqs, bbqs);
    } else if (bid < 1248) {
        prep_pack_qkv((bid - 816) * 256 + tid, wqm, bqm, Btqm, bbqm);
    } else if (bid < 1536) {
        prep_pack((bid - 1248) * 256 + tid, wproj, 180, 360, 384, Btproj);
    } else if (bid < 1824) {
        prep_pack((bid - 1536) * 256 + tid, w11, 360, 180, 192, Btf11);
    } else if (bid < 2112) {
        prep_pack((bid - 1824) * 256 + tid, w12, 360, 180, 192, Btf12);
    } else if (bid < 2400) {
        prep_pack((bid - 2112) * 256 + tid, w2, 180, 360, 384, Btf2);
    } else if (bid < 3552) {                       // zero attn pad cols 360..383
        int gi = (bid - 2400) * 256 + tid;         // < 294912
        int row = gi / 3, part = gi - row * 3;
        *(uint4*)&attn[(size_t)row * 384 + 360 + part * 8] = make_uint4(0u,0u,0u,0u);
    } else {                                       // pbW[t][n] = (pos_bias @ Wqm), q scaled
        int idx = (bid - 3552) * 256 + tid;        // < 36864 = 64 * 576
        int t = idx / 576, n = idx - t * 576;
        int three = n / 192;
        int rem = n - three * 192, nh = rem >> 5, hdp = rem & 31;
        float s = 0.f;
        if (hdp < 30) {
            int srcc = three * 180 + nh * 30 + hdp;
            const float* pr = posb + (size_t)t * 180;
            for (int k = 0; k < 180; k++)
                s = fmaf(pr[k], wqm[(size_t)k * 540 + srcc], s);
            if (three == 0) s *= SCALE_F;
        }
        pbW[idx] = s;
    }
}

// ---------------------------------------------------------------- LayerNorm (vectorized)
// ROLL selects rolled-window source addressing (LN1) vs linear (LN2).
template<bool ROLL>
__global__ __launch_bounds__(256) void k_ln(const float* __restrict__ x,
                                            const float* __restrict__ g,
                                            const float* __restrict__ b,
                                            bf16* __restrict__ xw)
{
    int row  = blockIdx.x * 4 + (threadIdx.x >> 6);
    int lane = threadIdx.x & 63;
    const float* src = ROLL ? (x + wrev_base(row)) : (x + (size_t)row * 180);
    float4 v = make_float4(0.f, 0.f, 0.f, 0.f);
    if (lane < 45) v = *(const float4*)&src[lane * 4];
    float s  = v.x + v.y + v.z + v.w;
    float ss = v.x*v.x + v.y*v.y + v.z*v.z + v.w*v.w;
    #pragma unroll
    for (int o = 32; o > 0; o >>= 1) { s += __shfl_xor(s, o, 64); ss += __shfl_xor(ss, o, 64); }
    float mean = s * (1.f/180.f);
    float var  = ss * (1.f/180.f) - mean*mean;
    float rstd = rsqrtf(var + 1e-5f);

    bf16* dst = xw + (size_t)row * 192;
    if (lane < 45) {
        float4 gv = *(const float4*)&g[lane * 4];
        float4 bv = *(const float4*)&b[lane * 4];
        float4 y;
        y.x = (v.x - mean) * rstd * gv.x + bv.x;
        y.y = (v.y - mean) * rstd * gv.y + bv.y;
        y.z = (v.z - mean) * rstd * gv.z + bv.z;
        y.w = (v.w - mean) * rstd * gv.w + bv.w;
        *(us4*)&dst[lane * 4] = pack4(y.x, y.y, y.z, y.w);
    } else if (lane < 48) {
        *(us4*)&dst[lane * 4] = (us4){0, 0, 0, 0};
    }
}

// ---------------------------------------------------------------- MFMA GEMM core v3 (proven)
// C[128 x 64] tile of A[M x KP](bf16) @ Bt[N][KP](bf16, pre-transposed).
// global_load_lds width=16; LDS linear [rows][64], content chunk-swizzled
// via pre-swizzled global source; ds_read applies same XOR. 2 barriers/K-step.
template<int KP, bool DUAL>
__device__ __forceinline__ void mm2(const bf16* __restrict__ A,
                                    const bf16* __restrict__ Bt1,
                                    const bf16* __restrict__ Bt2,
                                    bf16* As, bf16* Bs1, bf16* Bs2,
                                    int m0, int n0,
                                    f32x4 (&acc1)[2][4], f32x4 (&acc2)[2][4])
{
    const int tid = threadIdx.x;
    const int w = tid >> 6, l = tid & 63, q = l >> 4, c = l & 15;
    const int lr = l >> 3, lj = l & 7;
    const int swz = ((lj ^ lr) << 3);             // pre-swizzled source chunk (elems)
    #pragma unroll
    for (int ks = 0; ks < KP / 64; ks++) {
        #pragma unroll
        for (int e = 0; e < 4; e++) {             // A: 128 rows, 8 rows per wave-load
            int m = (e * 4 + w) * 8 + lr;
            gld16(&A[(size_t)(m0 + m) * KP + ks * 64 + swz], &As[((e * 4 + w) * 8) * 64]);
        }
        #pragma unroll
        for (int e = 0; e < 2; e++) {             // B: 64 rows
            int n = (e * 4 + w) * 8 + lr;
            gld16(&Bt1[(size_t)(n0 + n) * KP + ks * 64 + swz], &Bs1[((e * 4 + w) * 8) * 64]);
            if (DUAL)
                gld16(&Bt2[(size_t)(n0 + n) * KP + ks * 64 + swz], &Bs2[((e * 4 + w) * 8) * 64]);
        }
        __syncthreads();                          // drains vmcnt (gld writes landed)
        #pragma unroll
        for (int k32 = 0; k32 < 2; k32++) {
            int koff = (((k32 * 4 + q) ^ (c & 7)) << 3);
            short8 a[2];
            #pragma unroll
            for (int mt = 0; mt < 2; mt++)
                a[mt] = *(const short8*)&As[(w * 32 + mt * 16 + c) * 64 + koff];
            #pragma unroll
            for (int nt = 0; nt < 4; nt++) {
                short8 b1 = *(const short8*)&Bs1[(nt * 16 + c) * 64 + koff];
                #pragma unroll
                for (int mt = 0; mt < 2; mt++) acc1[mt][nt] = mfma16(a[mt], b1, acc1[mt][nt]);
                if (DUAL) {
                    short8 b2 = *(const short8*)&Bs2[(nt * 16 + c) * 64 + koff];
                    #pragma unroll
                    for (int mt = 0; mt < 2; mt++) acc2[mt][nt] = mfma16(a[mt], b2, acc2[mt][nt]);
                }
            }
        }
        __syncthreads();
    }
}

// epilogue LDS roundtrip swizzle (bf16 path): chunk ^= (row>>2)&7.
__device__ __forceinline__ int cs_idx(int row, int colt){
    return row * 64 + ((((colt >> 3) ^ ((row >> 2) & 7)) << 3) | (colt & 7));
}

// qkv GEMM: KP=192, N=576 packed; vectorized scatter to qkv via LDS roundtrip.
// MUT adds the precomputed fp32 pbW[(tok&63)][col] (pos_bias @ Wqm) in the
// epilogue -- xwm tensor eliminated (A is xw for both dispatches).
template<bool MUT>
__global__ __launch_bounds__(256) void k_qkv(const bf16* __restrict__ A,
                                             const bf16* __restrict__ Bt,
                                             const float* __restrict__ bb,
                                             const float* __restrict__ pbW,
                                             bf16* __restrict__ outq)
{
    __shared__ __align__(16) bf16 As[128 * 64];
    __shared__ __align__(16) bf16 Bs[64 * 64];
    int bid = xswz();                             // 6912 = 768 * 9, n-fastest
    int n0 = (bid % 9) * 64, m0 = (bid / 9) * 128;
    f32x4 a1[2][4] = {}, a2[2][4];
    mm2<192, false>(A, Bt, nullptr, As, Bs, nullptr, m0, n0, a1, a2);

    int tid = threadIdx.x, w = tid >> 6, l = tid & 63, q = l >> 4, c = l & 15;
    bf16* Cs = As;
    #pragma unroll
    for (int mt = 0; mt < 2; mt++)
      #pragma unroll
      for (int nt = 0; nt < 4; nt++)
        #pragma unroll
        for (int r = 0; r < 4; r++) {
            int row = w * 32 + mt * 16 + q * 4 + r;
            int colt = nt * 16 + c;
            float v = a1[mt][nt][r] + bb[n0 + colt];
            if (MUT) v += pbW[(size_t)(row & 63) * 576 + n0 + colt];
            Cs[cs_idx(row, colt)] = f2b(v);
        }
    __syncthreads();
    int win = m0 >> 7;
    #pragma unroll
    for (int e = 0; e < 4; e++) {
        int gi = e * 256 + tid;                   // < 1024
        int row = gi >> 3, j = gi & 7, c8 = j * 8;
        int col = n0 + c8;
        int three = col / 192, rem = col - three * 192;
        int nh = rem >> 5, hdp = rem & 31;
        bf16* dst = outq + (size_t)three * SZPE + ((size_t)(win * 6 + nh) * 128 + row) * 32 + hdp;
        *(uint4*)dst = *(const uint4*)&Cs[row * 64 + ((j ^ ((row >> 2) & 7)) << 3)];
    }
}

// proj GEMM: KP=384 (attn stride), N pad 192; window-reverse + roll + residual -> d_out.
__global__ __launch_bounds__(256) void k_proj(const bf16* __restrict__ A,
                                              const bf16* __restrict__ Bt,
                                              const float* __restrict__ bias,
                                              const float* __restrict__ xin,
                                              float* __restrict__ res)
{
    __shared__ __align__(16) char smem[24576];
    bf16*  As = (bf16*)smem;                      // 16384 B
    bf16*  Bs = (bf16*)(smem + 16384);            // 8192 B
    float* Cs = (float*)smem;                     // [64][76] = 19456 B per half
    int bid = xswz();                             // 2304 = 768 * 3
    int n0 = (bid % 3) * 64, m0 = (bid / 3) * 128;
    f32x4 a1[2][4] = {}, a2[2][4];
    mm2<384, false>(A, Bt, nullptr, As, Bs, nullptr, m0, n0, a1, a2);

    int tid = threadIdx.x, w = tid >> 6, l = tid & 63, q = l >> 4, c = l & 15;
    #pragma unroll
    for (int h = 0; h < 2; h++) {
        __syncthreads();                          // prev readers of Cs/As done
        if ((w >> 1) == h) {                      // waves 2h,2h+1 own rows h*64..+63
            #pragma unroll
            for (int mt = 0; mt < 2; mt++)
              #pragma unroll
              for (int nt = 0; nt < 4; nt++)
                #pragma unroll
                for (int r = 0; r < 4; r++) {
                    int rl = (w & 1) * 32 + mt * 16 + q * 4 + r;   // 0..63
                    Cs[rl * 76 + nt * 16 + c] = a1[mt][nt][r];
                }
        }
        __syncthreads();
        #pragma unroll
        for (int e = 0; e < 4; e++) {
            int slot = e * 256 + tid;             // < 1024: 64 rows x 16 quads
            int rl = slot >> 4, cq = slot & 15;
            int col = n0 + cq * 4;
            if (col < 180) {
                size_t base = wrev_base(m0 + h * 64 + rl) + col;
                float4 xi = *(const float4*)&xin[base];
                float4 bi = *(const float4*)&bias[col];
                const float* cp = &Cs[rl * 76 + cq * 4];
                float4 o;
                o.x = xi.x + cp[0] + bi.x;
                o.y = xi.y + cp[1] + bi.y;
                o.z = xi.z + cp[2] + bi.z;
                o.w = xi.w + cp[3] + bi.w;
                *(float4*)&res[base] = o;
            }
        }
    }
}

// fc1: KP=192, N pad 384 dual; gelu(x1)*x2 -> hid [98304][384] via LDS roundtrip.
__global__ __launch_bounds__(256) void k_fc1(const bf16* __restrict__ A,
                                             const bf16* __restrict__ Bt1,
                                             const float* __restrict__ bb1,
                                             const bf16* __restrict__ Bt2,
                                             const float* __restrict__ bb2,
                                             bf16* __restrict__ hid)
{
    __shared__ __align__(16) bf16 As[128 * 64];
    __shared__ __align__(16) bf16 Bs1[64 * 64];
    __shared__ __align__(16) bf16 Bs2[64 * 64];
    int bid = xswz();                             // 4608 = 768 * 6
    int n0 = (bid % 6) * 64, m0 = (bid / 6) * 128;
    f32x4 a1[2][4] = {}, a2[2][4] = {};
    mm2<192, true>(A, Bt1, Bt2, As, Bs1, Bs2, m0, n0, a1, a2);

    int tid = threadIdx.x, w = tid >> 6, l = tid & 63, q = l >> 4, c = l & 15;
    bf16* Cs = As;
    #pragma unroll
    for (int mt = 0; mt < 2; mt++)
      #pragma unroll
      for (int nt = 0; nt < 4; nt++)
        #pragma unroll
        for (int r = 0; r < 4; r++) {
            int row = w * 32 + mt * 16 + q * 4 + r;
            int colt = nt * 16 + c;
            int col = n0 + colt;
            float hv = 0.f;
            if (col < 360)
                hv = gelu_erf(a1[mt][nt][r] + bb1[col]) * (a2[mt][nt][r] + bb2[col]);
            Cs[cs_idx(row, colt)] = f2b(hv);
        }
    __syncthreads();
    #pragma unroll
    for (int e = 0; e < 4; e++) {
        int gi = e * 256 + tid;
        int row = gi >> 3, j = gi & 7, c8 = j * 8;
        *(uint4*)&hid[(size_t)(m0 + row) * 384 + n0 + c8] =
            *(const uint4*)&Cs[row * 64 + ((j ^ ((row >> 2) & 7)) << 3)];
    }
}

// fc2: KP=384 (hid stride), N pad 192; out += hid@w2 + b (in-place fp32).
__global__ __launch_bounds__(256) void k_fc2(const bf16* __restrict__ A,
                                             const bf16* __restrict__ Bt,
                                             const float* __restrict__ bias,
                                             float* __restrict__ out)
{
    __shared__ __align__(16) char smem[24576];
    bf16*  As = (bf16*)smem;
    bf16*  Bs = (bf16*)(smem + 16384);
    float* Cs = (float*)smem;                     // [64][76]
    int bid = xswz();                             // 2304
    int n0 = (bid % 3) * 64, m0 = (bid / 3) * 128;
    f32x4 a1[2][4] = {}, a2[2][4];
    mm2<384, false>(A, Bt, nullptr, As, Bs, nullptr, m0, n0, a1, a2);

    int tid = threadIdx.x, w = tid >> 6, l = tid & 63, q = l >> 4, c = l & 15;
    #pragma unroll
    for (int h = 0; h < 2; h++) {
        __syncthreads();
        if ((w >> 1) == h) {
            #pragma unroll
            for (int mt = 0; mt < 2; mt++)
              #pragma unroll
              for (int nt = 0; nt < 4; nt++)
                #pragma unroll
                for (int r = 0; r < 4; r++) {
                    int rl = (w & 1) * 32 + mt * 16 + q * 4 + r;
                    Cs[rl * 76 + nt * 16 + c] = a1[mt][nt][r];
                }
        }
        __syncthreads();
        #pragma unroll
        for (int e = 0; e < 4; e++) {
            int slot = e * 256 + tid;
            int rl = slot >> 4, cq = slot & 15;
            int col = n0 + cq * 4;
            if (col < 180) {
                size_t idx = (size_t)(m0 + h * 64 + rl) * 180 + col;
                float4 ov = *(const float4*)&out[idx];
                float4 bi = *(const float4*)&bias[col];
                const float* cp = &Cs[rl * 76 + cq * 4];
                ov.x += cp[0] + bi.x;
                ov.y += cp[1] + bi.y;
                ov.z += cp[2] + bi.z;
                ov.w += cp[3] + bi.w;
                *(float4*)&out[idx] = ov;
            }
        }
    }
}

// ---------------------------------------------------------------- MFMA attention v3
// Q/K fragments direct from global; mask analytic; bias from transposed bf16 table;
// Vts/Ps XOR-swizzled. MUT: block-diagonal -- each wave computes only its valid
// 64-col half (wave-uniform), halving QK^T, softmax, and PV work.
template<bool MUT>
__global__ __launch_bounds__(256) void k_attn(const bf16* __restrict__ qkv,
                                              const bf16* __restrict__ biasrT,
                                              bf16* __restrict__ aout)
{
    __shared__ __align__(16) bf16 Vts[32 * 136];
    __shared__ __align__(16) bf16 Ps[128 * 136];

    int wh = blockIdx.x, win = wh / 6, nh = wh - win * 6;
    const bf16* qg = qkv + (size_t)wh * 4096;
    const bf16* kg = qg + (size_t)SZPE;
    const bf16* vg = qg + 2 * (size_t)SZPE;
    int tid = threadIdx.x, w = tid >> 6, l = tid & 63, q = l >> 4, c = l & 15;

    constexpr int NT = MUT ? 4 : 8;               // col-tiles computed per wave
    const int colbase = MUT ? ((w < 2) ? 0 : 64) : 0;   // wave-uniform

    // stage V transposed (swizzled): 2 x uint4 global loads per thread
    #pragma unroll
    for (int e = 0; e < 2; e++) {
        int base = (e * 256 + tid) * 8;          // < 4096
        int tok = base >> 5, hd0 = base & 31;
        uint4 vv = *(const uint4*)&vg[base];
        const bf16* pv = (const bf16*)&vv;
        #pragma unroll
        for (int i = 0; i < 8; i++) {
            int hd = hd0 + i;
            Vts[hd * 136 + (tok ^ (((hd >> 3) & 3) << 3))] = pv[i];
        }
    }

    // QK^T direct from global (fragments are contiguous 16B in [128][32] layout)
    f32x4 S[2][NT];
    #pragma unroll
    for (int mt = 0; mt < 2; mt++)
        #pragma unroll
        for (int nt = 0; nt < NT; nt++) S[mt][nt] = (f32x4){0.f, 0.f, 0.f, 0.f};
    {
        short8 a[2];
        #pragma unroll
        for (int mt = 0; mt < 2; mt++) {
            int rq = w * 32 + mt * 16 + c;
            if (MUT) rq ^= 64;                   // swap halves for mutual attn
            a[mt] = *(const short8*)&qg[rq * 32 + q * 8];
        }
        #pragma unroll
        for (int nt = 0; nt < NT; nt++) {
            short8 b = *(const short8*)&kg[(colbase + nt * 16 + c) * 32 + q * 8];
            #pragma unroll
            for (int mt = 0; mt < 2; mt++) S[mt][nt] = mfma16(a[mt], b, S[mt][nt]);
        }
    }

    // region labels for analytic mask
    int rcnt[2][4], ccnt[NT];
    #pragma unroll
    for (int mt = 0; mt < 2; mt++)
        #pragma unroll
        for (int r = 0; r < 4; r++) {
            int row = w * 32 + mt * 16 + q * 4 + r;
            rcnt[mt][r] = wincnt(win, MUT ? (row & 63) : row);
        }
    #pragma unroll
    for (int nt = 0; nt < NT; nt++) {
        int col = colbase + nt * 16 + c;
        ccnt[nt] = wincnt(win, MUT ? (col & 63) : col);
    }

    float mx[2][4];
    #pragma unroll
    for (int mt = 0; mt < 2; mt++)
      #pragma unroll
      for (int r = 0; r < 4; r++) mx[mt][r] = -3.0e38f;

    #pragma unroll
    for (int mt = 0; mt < 2; mt++)
      #pragma unroll
      for (int nt = 0; nt < NT; nt++) {
        float bv[4];
        if (!MUT) {
            int col = nt * 16 + c;
            us4 bb = *(const us4*)&biasrT[((size_t)(nh * 128 + col)) * 128
                                          + w * 32 + mt * 16 + q * 4];
            #pragma unroll
            for (int r = 0; r < 4; r++) bv[r] = bu2f(bb[r]);
        }
        #pragma unroll
        for (int r = 0; r < 4; r++) {
            float s = S[mt][nt][r];
            if (MUT) {
                s = (rcnt[mt][r] == ccnt[nt]) ? s : s - 100.f;
            } else {
                s += bv[r];
                if (rcnt[mt][r] != ccnt[nt]) s -= 100.f;
            }
            S[mt][nt][r] = s;
            mx[mt][r] = fmaxf(mx[mt][r], s);
        }
      }
    #pragma unroll
    for (int mt = 0; mt < 2; mt++)
      #pragma unroll
      for (int r = 0; r < 4; r++) {
          float m = mx[mt][r];
          #pragma unroll
          for (int o = 1; o < 16; o <<= 1) m = fmaxf(m, __shfl_xor(m, o, 64));
          mx[mt][r] = m;
      }

    float sm[2][4] = {};
    #pragma unroll
    for (int mt = 0; mt < 2; mt++)
      #pragma unroll
      for (int nt = 0; nt < NT; nt++)
        #pragma unroll
        for (int r = 0; r < 4; r++) {
            float p = __expf(S[mt][nt][r] - mx[mt][r]);
            sm[mt][r] += p;
            Ps[(w * 32 + mt * 16 + q * 4 + r) * 136 + ((colbase + nt * 16 + c) ^ (q << 3))] = f2b(p);
        }
    #pragma unroll
    for (int mt = 0; mt < 2; mt++)
      #pragma unroll
      for (int r = 0; r < 4; r++) {
          float s = sm[mt][r];
          #pragma unroll
          for (int o = 1; o < 16; o <<= 1) s += __shfl_xor(s, o, 64);
          sm[mt][r] = s;
      }
    __syncthreads();                              // Vts + Ps ready

    f32x4 O[2][2];
    #pragma unroll
    for (int mt = 0; mt < 2; mt++)
        #pragma unroll
        for (int nt = 0; nt < 2; nt++) O[mt][nt] = (f32x4){0.f, 0.f, 0.f, 0.f};
    #pragma unroll
    for (int ksr = 0; ksr < (MUT ? 2 : 4); ksr++) {
        int ks = MUT ? ((colbase >> 5) + ksr) : ksr;
        short8 a[2];
        #pragma unroll
        for (int mt = 0; mt < 2; mt++) {
            int row = w * 32 + mt * 16 + c;
            int xr = ((c >> 2) & 3) << 3;         // = (row>>2)&3, matches writer q
            a[mt] = *(const short8*)&Ps[row * 136 + (ks * 32 + ((q << 3) ^ xr))];
        }
        #pragma unroll
        for (int nt = 0; nt < 2; nt++) {
            int hd = nt * 16 + c;
            int xv = ((hd >> 3) & 3) << 3;
            short8 b = *(const short8*)&Vts[hd * 136 + (ks * 32 + ((q << 3) ^ xv))];
            #pragma unroll
            for (int mt = 0; mt < 2; mt++) O[mt][nt] = mfma16(a[mt], b, O[mt][nt]);
        }
    }

    #pragma unroll
    for (int mt = 0; mt < 2; mt++)
      #pragma unroll
      for (int r = 0; r < 4; r++) {
          int row = w * 32 + mt * 16 + q * 4 + r;
          float inv = 1.f / sm[mt][r];
          #pragma unroll
          for (int nt = 0; nt < 2; nt++) {
              int col = nt * 16 + c;
              if (col < 30)
                  aout[((size_t)win * 128 + row) * 384 + (MUT ? 0 : 180) + nh * 30 + col] =
                      f2b(O[mt][nt][r] * inv);
          }
      }
}

// ---------------------------------------------------------------- launch
extern "C" void kernel_launch(void* const* d_in, const int* in_sizes, int n_in,
                              void* d_out, int out_size, void* d_ws, size_t ws_size,
                              hipStream_t stream)
{
    const float* x     = (const float*)d_in[0];
    const float* mask  = (const float*)d_in[1];
    const float* g1    = (const float*)d_in[2];
    const float* b1    = (const float*)d_in[3];
    const float* g2    = (const float*)d_in[4];
    const float* b2    = (const float*)d_in[5];
    const float* wqs   = (const float*)d_in[6];
    const float* bqs   = (const float*)d_in[7];
    const float* wqm   = (const float*)d_in[8];
    const float* bqm   = (const float*)d_in[9];
    const float* rpb   = (const float*)d_in[10];
    const float* posb  = (const float*)d_in[11];
    const float* wproj = (const float*)d_in[12];
    const float* bproj = (const float*)d_in[13];
    const float* w11   = (const float*)d_in[14];
    const float* bf11  = (const float*)d_in[15];
    const float* w12   = (const float*)d_in[16];
    const float* bf12  = (const float*)d_in[17];
    const float* w2    = (const float*)d_in[18];
    const float* bf2   = (const float*)d_in[19];
    const int*   rpi   = (const int*)d_in[20];
    float* out = (float*)d_out;
    (void)mask;   // mask is computed analytically in k_attn

    const size_t need = 265671168;
    if (ws_size < need) { fprintf(stderr, "[tmsa] ws too small: %zu < %zu\n", ws_size, need); return; }

    char* W = (char*)d_ws;
    bf16*  xw     = (bf16*)W;                              // [98304][192]
    float* pbW    = (float*)(W + 37748736);                // [64][576] fp32
    bf16*  attn   = (bf16*)(W + 75497472);                 // [98304][384]
    bf16*  qkv    = (bf16*)(W + 150994944);                // [3][4608][128][32]
    bf16*  biasrT = (bf16*)(W + 264241152);                // [6][128][128] bf16 (transposed)
    bf16*  Btqs   = (bf16*)(W + 264634368);                // [576][192]
    bf16*  Btqm   = (bf16*)(W + 264855552);                // [576][192]
    float* bbqs   = (float*)(W + 265076736);               // [576]
    float* bbqm   = (float*)(W + 265079040);               // [576]
    bf16*  Btproj = (bf16*)(W + 265081344);                // [192][384]
    bf16*  Btf11  = (bf16*)(W + 265228800);                // [384][192]
    bf16*  Btf12  = (bf16*)(W + 265376256);                // [384][192]
    bf16*  Btf2   = (bf16*)(W + 265523712);                // [192][384]

    k_prep<<<dim3(3696), 256, 0, stream>>>(rpb, rpi, biasrT,
                                           wqs, bqs, Btqs, bbqs,
                                           wqm, bqm, Btqm, bbqm,
                                           wproj, Btproj, w11, Btf11,
                                           w12, Btf12, w2, Btf2, attn,
                                           posb, pbW);

    k_ln<true><<<dim3(24576), 256, 0, stream>>>(x, g1, b1, xw);
    k_qkv<false><<<dim3(6912), 256, 0, stream>>>(xw, Btqs, bbqs, nullptr, qkv);
    k_attn<false><<<dim3(4608), 256, 0, stream>>>(qkv, biasrT, attn);
    k_qkv<true><<<dim3(6912), 256, 0, stream>>>(xw, Btqm, bbqm, pbW, qkv);
    k_attn<true><<<dim3(4608), 256, 0, stream>>>(qkv, biasrT, attn);
    k_proj<<<dim3(2304), 256, 0, stream>>>(attn, Btproj, bproj, x, out);
    k_ln<false><<<dim3(24576), 256, 0, stream>>>(out, g2, b2, xw);
    k_fc1<<<dim3(4608), 256, 0, stream>>>(xw, Btf11, bf11, Btf12, bf12, attn);
    k_fc2<<<dim3(2304), 256, 0, stream>>>(attn, Btf2, bf2, out);
}